// Round 12
// baseline (528.115 us; speedup 1.0000x reference)
//
#include <hip/hip_runtime.h>
#include <math.h>

// Problem constants (from reference)
#define Nn 50000
#define MPAD 50048  // Nn padded to multiple of 128 (GEMM row tiles, no guards)
#define Ee 500000
#define Cc 256
#define Hh 128
#define Ll 4
#define Gg 64
#define Kk 8
#define NCc 2

#define NB 196  // ceil(Nn/256)

typedef __attribute__((ext_vector_type(8))) short short8;
typedef __attribute__((ext_vector_type(4))) float f32x4;
typedef __attribute__((ext_vector_type(2))) float f32x2;

#define RFL __builtin_amdgcn_readfirstlane

__device__ __forceinline__ unsigned short f2bf(float f) {
    union { float f; unsigned int u; } v;
    v.f = f;
    unsigned int u = v.u;
    return (unsigned short)((u + 0x7FFFu + ((u >> 16) & 1u)) >> 16);
}
__device__ __forceinline__ float bf2f(unsigned short s) {
    union { float f; unsigned int u; } v;
    v.u = ((unsigned int)s) << 16;
    return v.f;
}
__device__ __forceinline__ float bf2f_lo(unsigned int u) {
    union { float f; unsigned int u; } v;
    v.u = u << 16;
    return v.f;
}
__device__ __forceinline__ float bf2f_hi(unsigned int u) {
    union { float f; unsigned int u; } v;
    v.u = u & 0xffff0000u;
    return v.f;
}

// ---------------- CSR build ----------------

__global__ void hist_kernel(const int* __restrict__ dst, int* __restrict__ deg) {
    int e = blockIdx.x * 256 + threadIdx.x;
    if (e < Ee) atomicAdd(&deg[dst[e]], 1);
}

__global__ __launch_bounds__(256) void bsum_kernel(const int* __restrict__ deg,
                                                   int* __restrict__ bsum) {
    __shared__ int ws[4];
    int t = threadIdx.x;
    int i = blockIdx.x * 256 + t;
    int v = (i < Nn) ? deg[i] : 0;
#pragma unroll
    for (int o = 32; o; o >>= 1) v += __shfl_down(v, o, 64);
    if ((t & 63) == 0) ws[t >> 6] = v;
    __syncthreads();
    if (t == 0) bsum[blockIdx.x] = ws[0] + ws[1] + ws[2] + ws[3];
}

__global__ __launch_bounds__(256) void bscan_kernel(const int* __restrict__ bsum,
                                                    int* __restrict__ boff,
                                                    int* __restrict__ off) {
    __shared__ int sc[256];
    int t = threadIdx.x;
    int v = (t < NB) ? bsum[t] : 0;
    sc[t] = v;
    __syncthreads();
    for (int o = 1; o < 256; o <<= 1) {
        int u = (t >= o) ? sc[t - o] : 0;
        __syncthreads();
        sc[t] += u;
        __syncthreads();
    }
    if (t < NB) boff[t] = sc[t] - v;  // exclusive
    if (t == NB - 1) off[Nn] = sc[t];
}

__global__ __launch_bounds__(256) void offsets_kernel(const int* __restrict__ deg,
                                                      const int* __restrict__ boff,
                                                      int* __restrict__ off,
                                                      int* __restrict__ pos) {
    __shared__ int sc[256];
    int t = threadIdx.x;
    int i = blockIdx.x * 256 + t;
    int v = (i < Nn) ? deg[i] : 0;
    sc[t] = v;
    __syncthreads();
    for (int o = 1; o < 256; o <<= 1) {
        int u = (t >= o) ? sc[t - o] : 0;
        __syncthreads();
        sc[t] += u;
        __syncthreads();
    }
    int excl = sc[t] - v + boff[blockIdx.x];
    if (i < Nn) {
        off[i] = excl;
        pos[i] = excl;
    }
}

__global__ void scatter_kernel(const int* __restrict__ src, const int* __restrict__ dst,
                               const float* __restrict__ attr, int* __restrict__ pos,
                               int2* __restrict__ sedge) {
    int e = blockIdx.x * 256 + threadIdx.x;
    if (e < Ee) {
        int d = dst[e];
        int p = atomicAdd(&pos[d], 1);
        sedge[p] = make_int2(src[e], __float_as_int(attr[e]));
    }
}

// ---------------- weight convert + transpose to bf16 [N][K] ----------------
// wt layout: [0, 65536)            proj  [256 n][256 k]  (n<128: lin_src col, else lin_dst)
//            [65536, 196608)       w1[l] [256 n][128 k]
//            [196608, 327680)      w2[l] [128 n][256 k]

__global__ void wconv_kernel(const float* __restrict__ lin_src_w,
                             const float* __restrict__ lin_dst_w,
                             const float* __restrict__ mlp_w1,
                             const float* __restrict__ mlp_w2,
                             unsigned short* __restrict__ wt) {
    int idx = blockIdx.x * 256 + threadIdx.x;
    if (idx >= 327680) return;
    float val;
    if (idx < 65536) {
        int n = idx >> 8, k = idx & 255;
        val = (n < 128) ? lin_src_w[k * 128 + n] : lin_dst_w[k * 128 + (n - 128)];
    } else if (idx < 196608) {
        int r = idx - 65536;
        int l = r >> 15, e = r & 32767;
        int n = e >> 7, k = e & 127;
        val = mlp_w1[(size_t)l * 32768 + k * 256 + n];
    } else {
        int r = idx - 196608;
        int l = r >> 15, e = r & 32767;
        int n = e >> 8, k = e & 255;
        val = mlp_w2[(size_t)l * 32768 + k * 128 + n];
    }
    wt[idx] = f2bf(val);
}

// ---------------- x fp32 -> bf16 (one-time, vectorized) ----------------

__global__ __launch_bounds__(256) void xconv_kernel(const float* __restrict__ x,
                                                    unsigned short* __restrict__ xbf) {
    int idx = blockIdx.x * 256 + threadIdx.x;  // 8 elems per thread
    if (idx >= (Nn * Cc) / 8) return;
    const float4* p = (const float4*)(x) + (size_t)idx * 2;
    float4 v0 = p[0], v1 = p[1];
    unsigned short t[8];
    t[0] = f2bf(v0.x); t[1] = f2bf(v0.y); t[2] = f2bf(v0.z); t[3] = f2bf(v0.w);
    t[4] = f2bf(v1.x); t[5] = f2bf(v1.y); t[6] = f2bf(v1.z); t[7] = f2bf(v1.w);
    *(short8*)(xbf + (size_t)idx * 8) = *(short8*)t;
}

#define GLOAD16(gp, lp)                                                                       \
    __builtin_amdgcn_global_load_lds(                                                         \
        (const __attribute__((address_space(1))) unsigned int*)(gp),                          \
        (__attribute__((address_space(3))) unsigned int*)(lp), 16, 0, 0)

// ---------------- projection GEMM: xsd = x @ [Wsrc|Wdst] + [bsrc|bdst] ----------------
// 128x128 tile, BK=32, 4 waves, depth-2 prefetch (3 LDS buffers, counted vmcnt).
// Epilogue staged through LDS -> coalesced short8 stores.

__global__ __launch_bounds__(256) void proj_kernel(
    const unsigned short* __restrict__ A, const unsigned short* __restrict__ Bt,
    const float* __restrict__ bias, const float* __restrict__ bias2,
    unsigned short* __restrict__ Cout) {
    __shared__ __align__(16) unsigned short SH[24576];  // 48KB: 3xA(8KB) + 3xB(8KB); C reuse
    int tid = threadIdx.x;
    int wave = tid >> 6, lane = tid & 63;
    int wr = wave >> 1, wc = wave & 1;
    int lrow = lane & 15, quad = lane >> 4;
    int m0 = blockIdx.y * 128, n0 = blockIdx.x * 128;
    const int K = 256;

    const unsigned short* ag0 = A + (size_t)(m0 + (tid >> 2)) * K + (tid & 3) * 8;
    const unsigned short* ag1 = A + (size_t)(m0 + 64 + (tid >> 2)) * K + (tid & 3) * 8;
    const unsigned short* bg0 = Bt + (size_t)(n0 + (tid >> 2)) * K + (tid & 3) * 8;
    const unsigned short* bg1 = Bt + (size_t)(n0 + 64 + (tid >> 2)) * K + (tid & 3) * 8;

    f32x4 acc[4][4];
#pragma unroll
    for (int i = 0; i < 4; i++)
#pragma unroll
        for (int j = 0; j < 4; j++) acc[i][j] = (f32x4){0.f, 0.f, 0.f, 0.f};

    auto stage = [&](int buf, int koff) {
        GLOAD16(ag0 + koff, SH + buf * 4096 + wave * 512);
        GLOAD16(ag1 + koff, SH + buf * 4096 + 2048 + wave * 512);
        GLOAD16(bg0 + koff, SH + 12288 + buf * 4096 + wave * 512);
        GLOAD16(bg1 + koff, SH + 12288 + buf * 4096 + 2048 + wave * 512);
    };

    const int ntiles = 8;
    stage(0, 0);
    stage(1, 32);
    for (int t = 0; t < ntiles; ++t) {
        if (t + 1 < ntiles) {
            asm volatile("s_waitcnt vmcnt(4)\n\ts_barrier" ::: "memory");
        } else {
            asm volatile("s_waitcnt vmcnt(0)\n\ts_barrier" ::: "memory");
        }
        if (t + 2 < ntiles) stage((t + 2) % 3, (t + 2) * 32);
        int cur = t % 3;
        const unsigned short* As = SH + cur * 4096;
        const unsigned short* Bs = SH + 12288 + cur * 4096;
        short8 af[4], bfr[4];
#pragma unroll
        for (int mt = 0; mt < 4; mt++)
            af[mt] = *(const short8*)&As[(wr * 64 + mt * 16 + lrow) * 32 + quad * 8];
#pragma unroll
        for (int nf = 0; nf < 4; nf++)
            bfr[nf] = *(const short8*)&Bs[(wc * 64 + nf * 16 + lrow) * 32 + quad * 8];
#pragma unroll
        for (int mt = 0; mt < 4; mt++)
#pragma unroll
            for (int nf = 0; nf < 4; nf++)
                acc[mt][nf] = __builtin_amdgcn_mfma_f32_16x16x32_bf16(af[mt], bfr[nf],
                                                                     acc[mt][nf], 0, 0, 0);
    }

    __syncthreads();  // all frag reads done; reuse SH for C tile
    unsigned short* Cl = SH;  // [128][128] bf16 = 32KB
#pragma unroll
    for (int nf = 0; nf < 4; nf++) {
        int gc = n0 + wc * 64 + nf * 16 + lrow;
        float bs = (gc >= 128) ? bias2[gc - 128] : bias[gc];
        int col = wc * 64 + nf * 16 + lrow;
#pragma unroll
        for (int mt = 0; mt < 4; mt++)
#pragma unroll
            for (int r = 0; r < 4; r++)
                Cl[(wr * 64 + mt * 16 + quad * 4 + r) * 128 + col] = f2bf(acc[mt][nf][r] + bs);
    }
    __syncthreads();
#pragma unroll
    for (int p = 0; p < 8; p++) {
        int vid = p * 256 + tid;
        int row = vid >> 4, cg = (vid & 15) * 8;
        short8 v = *(const short8*)&Cl[row * 128 + cg];
        *(short8*)(Cout + (size_t)(m0 + row) * 256 + n0 + cg) = v;
    }
}

// ---------------- fused per-layer MLP (register-direct GEMMs, barrier-light) ----------
// hbuf (+)= agg @ W1 -> BN -> ReLU -> @ W2 + b2; next-layer prenorm rbuf fused.
// A and B fragments are loaded DIRECT from global into registers: W1/W2 are 64KB
// (L2/L1-resident across all 782 blocks) and the 16KB A tile gets full L1 reuse
// across K-tiles (each tile reads 64B/row of 256B rows; 4 tiles cover the row).
// No LDS staging -> no K-loop barriers (3 barriers/block total, was ~14) and LDS
// drops to Hm only (33.8KB, C2 reuses it exactly) -> 4 blocks/CU (was 2).
// Round-11 lesson: pool fusion via LDS atomics serialized (1.2M bank conflicts,
// l=3 75us) -> reverted to the separate pool kernel.

__global__ __launch_bounds__(256) void mlp_kernel(
    const unsigned short* __restrict__ A,    // aggout [MPAD][128] bf16
    const unsigned short* __restrict__ W1,   // [256 n][128 k] bf16
    const unsigned short* __restrict__ W2,   // [128 n][256 k] bf16
    const float* __restrict__ b1, const float* __restrict__ bn_g,
    const float* __restrict__ bn_b, const float* __restrict__ bn_m,
    const float* __restrict__ bn_v, const float* __restrict__ b2,
    const float* __restrict__ pn_g, const float* __restrict__ pn_b,
    const float* __restrict__ pn_m, const float* __restrict__ pn_v,
    float* __restrict__ hbuf, unsigned short* __restrict__ rbuf, int rmw) {
    __shared__ __align__(16) unsigned short Hm[64 * 264];  // 33.8KB; C2 [64][132] f32 reuse

    int tid = threadIdx.x;
    int wave = tid >> 6, lane = tid & 63;
    int lrow = lane & 15, quad = lane >> 4;
    int m0 = blockIdx.x * 64;

    // ---- phase 1: Hm = relu(BN(A[m0:m0+64] @ W1 + b1))  (64x256), all-register ----
    f32x4 acc1[4][4];
#pragma unroll
    for (int i = 0; i < 4; i++)
#pragma unroll
        for (int j = 0; j < 4; j++) acc1[i][j] = (f32x4){0.f, 0.f, 0.f, 0.f};
#pragma unroll
    for (int t = 0; t < 4; t++) {
        short8 af[4], bfr[4];
#pragma unroll
        for (int mt = 0; mt < 4; mt++)
            af[mt] = *(const short8*)(A + (size_t)(m0 + mt * 16 + lrow) * 128 +
                                      t * 32 + quad * 8);
#pragma unroll
        for (int nf = 0; nf < 4; nf++)
            bfr[nf] = *(const short8*)(W1 + (size_t)(wave * 64 + nf * 16 + lrow) * 128 +
                                       t * 32 + quad * 8);
#pragma unroll
        for (int mt = 0; mt < 4; mt++)
#pragma unroll
            for (int nf = 0; nf < 4; nf++)
                acc1[mt][nf] = __builtin_amdgcn_mfma_f32_16x16x32_bf16(af[mt], bfr[nf],
                                                                      acc1[mt][nf], 0, 0, 0);
    }
    // epilogue 1 -> Hm (LDS only)
#pragma unroll
    for (int nf = 0; nf < 4; nf++) {
        int gc = wave * 64 + nf * 16 + lrow;
        float bs = b1[gc];
        float g = bn_g[gc], bb = bn_b[gc], mm = bn_m[gc];
        float inv = rsqrtf(bn_v[gc] + 1e-5f);
#pragma unroll
        for (int mt = 0; mt < 4; mt++)
#pragma unroll
            for (int r = 0; r < 4; r++) {
                float v = acc1[mt][nf][r] + bs;
                v = fmaxf(g * (v - mm) * inv + bb, 0.f);
                Hm[(mt * 16 + quad * 4 + r) * 264 + gc] = f2bf(v);
            }
    }
    __syncthreads();  // Hm complete (cross-wave)

    // ---- phase 2: C2 = Hm @ W2 + b2  (64x128); A from LDS, B direct from L2 ----
    f32x4 acc2[4][2];
#pragma unroll
    for (int i = 0; i < 4; i++)
#pragma unroll
        for (int j = 0; j < 2; j++) acc2[i][j] = (f32x4){0.f, 0.f, 0.f, 0.f};
#pragma unroll
    for (int t = 0; t < 8; t++) {
        short8 af[4], bfr[2];
#pragma unroll
        for (int mt = 0; mt < 4; mt++)
            af[mt] = *(const short8*)&Hm[(mt * 16 + lrow) * 264 + t * 32 + quad * 8];
#pragma unroll
        for (int nf = 0; nf < 2; nf++)
            bfr[nf] = *(const short8*)(W2 + (size_t)(wave * 32 + nf * 16 + lrow) * 256 +
                                       t * 32 + quad * 8);
#pragma unroll
        for (int mt = 0; mt < 4; mt++)
#pragma unroll
            for (int nf = 0; nf < 2; nf++)
                acc2[mt][nf] = __builtin_amdgcn_mfma_f32_16x16x32_bf16(af[mt], bfr[nf],
                                                                      acc2[mt][nf], 0, 0, 0);
    }
    __syncthreads();  // all Hm reads done; reuse as fp32 C2 [64][132]

    float* C2 = (float*)Hm;
#pragma unroll
    for (int nf = 0; nf < 2; nf++) {
        int gc = wave * 32 + nf * 16 + lrow;
        float bs = b2[gc];
#pragma unroll
        for (int mt = 0; mt < 4; mt++)
#pragma unroll
            for (int r = 0; r < 4; r++)
                C2[(mt * 16 + quad * 4 + r) * 132 + gc] = acc2[mt][nf][r] + bs;
    }
    __syncthreads();
#pragma unroll
    for (int p = 0; p < 8; p++) {
        int vid = p * 256 + tid;
        int row = vid >> 5, c4 = (vid & 31) * 4;
        f32x4 v = *(const f32x4*)&C2[row * 132 + c4];
        float* hp = hbuf + (size_t)(m0 + row) * 128 + c4;
        if (rmw) v += *(const f32x4*)hp;
        *(f32x4*)hp = v;
        if (pn_g) {
            f32x4 pg = *(const f32x4*)&pn_g[c4];
            f32x4 pb = *(const f32x4*)&pn_b[c4];
            f32x4 pm = *(const f32x4*)&pn_m[c4];
            f32x4 pv = *(const f32x4*)&pn_v[c4];
            float r0 = fmaxf(pg[0] * (v[0] - pm[0]) * rsqrtf(pv[0] + 1e-5f) + pb[0], 0.f);
            float r1 = fmaxf(pg[1] * (v[1] - pm[1]) * rsqrtf(pv[1] + 1e-5f) + pb[1], 0.f);
            float r2 = fmaxf(pg[2] * (v[2] - pm[2]) * rsqrtf(pv[2] + 1e-5f) + pb[2], 0.f);
            float r3 = fmaxf(pg[3] * (v[3] - pm[3]) * rsqrtf(pv[3] + 1e-5f) + pb[3], 0.f);
            unsigned int w0 = (unsigned int)f2bf(r0) | ((unsigned int)f2bf(r1) << 16);
            unsigned int w1 = (unsigned int)f2bf(r2) | ((unsigned int)f2bf(r3) << 16);
            uint2 pk = make_uint2(w0, w1);
            *(uint2*)(rbuf + (size_t)(m0 + row) * 128 + c4) = pk;
        }
    }
}

// ---------------- Fused GENConv aggregation (2 nodes/wave, interleaved chains) --------
// Each wave owns nodes d0,d1; main loop keeps both nodes' gather chains in flight.
// All wave-uniform control scalarized via readfirstlane (round-10 win).
// Per-edge +1e-7 folded into the final quotient (softmax shift-invariance, exact).

template <int XSS>
__global__ __launch_bounds__(256) void agg_kernel(
    const unsigned short* __restrict__ xs,
    const unsigned short* __restrict__ xd, int xds,
    const int2* __restrict__ sedge, const int* __restrict__ off,
    const float* __restrict__ ew, const float* __restrict__ eb,
    const float* __restrict__ tptr, unsigned short* __restrict__ outb) {
    int wave = threadIdx.x >> 6;
    int lane = threadIdx.x & 63;
    int d0 = blockIdx.x * 8 + wave * 2;  // Nn % 8 == 0, d0,d1 always < Nn
    int d1 = d0 + 1;
    int f0 = lane * 2;
    unsigned int uda = *(const unsigned int*)(xd + (size_t)d0 * xds + f0);
    unsigned int udb = *(const unsigned int*)(xd + (size_t)d1 * xds + f0);
    f32x2 wv = *(const f32x2*)(ew + f0);
    f32x2 bv = *(const f32x2*)(eb + f0);
    float c = tptr[0] * 1.44269504088896f;
    const f32x2 zz = {0.f, 0.f};
    int s0a = RFL(off[d0]), s1a = RFL(off[d0 + 1]);
    int s0b = RFL(off[d1]), s1b = RFL(off[d1 + 1]);
    f32x2 dena = {0.f, 0.f}, numa = {0.f, 0.f};
    f32x2 denb = {0.f, 0.f}, numb = {0.f, 0.f};

#define EDGE2(u, av, den, num)                                      \
    {                                                               \
        f32x2 xv = {bf2f_lo(u), bf2f_hi(u)};                        \
        f32x2 m = __builtin_elementwise_max(xv + bv + (av)*wv, zz); \
        f32x2 e;                                                    \
        e.x = __builtin_amdgcn_exp2f(m.x * c);                      \
        e.y = __builtin_amdgcn_exp2f(m.y * c);                      \
        den += e;                                                   \
        num += m * e;                                               \
    }
#define EDGE2M(u, av, mk, den, num)                                 \
    {                                                               \
        f32x2 xv = {bf2f_lo(u), bf2f_hi(u)};                        \
        f32x2 m = __builtin_elementwise_max(xv + bv + (av)*wv, zz); \
        f32x2 e;                                                    \
        e.x = __builtin_amdgcn_exp2f(m.x * c) * (mk);               \
        e.y = __builtin_amdgcn_exp2f(m.y * c) * (mk);               \
        den += e;                                                   \
        num += m * e;                                               \
    }
#define LOADMETA(jv, ii, aa)                                   \
    {                                                          \
        int4 q0 = *(const int4*)(sedge + (jv));                \
        int4 q1 = *(const int4*)(sedge + (jv) + 2);            \
        int4 q2 = *(const int4*)(sedge + (jv) + 4);            \
        int4 q3 = *(const int4*)(sedge + (jv) + 6);            \
        ii[0] = RFL(q0.x); aa[0] = __int_as_float(RFL(q0.y));  \
        ii[1] = RFL(q0.z); aa[1] = __int_as_float(RFL(q0.w));  \
        ii[2] = RFL(q1.x); aa[2] = __int_as_float(RFL(q1.y));  \
        ii[3] = RFL(q1.z); aa[3] = __int_as_float(RFL(q1.w));  \
        ii[4] = RFL(q2.x); aa[4] = __int_as_float(RFL(q2.y));  \
        ii[5] = RFL(q2.z); aa[5] = __int_as_float(RFL(q2.w));  \
        ii[6] = RFL(q3.x); aa[6] = __int_as_float(RFL(q3.y));  \
        ii[7] = RFL(q3.z); aa[7] = __int_as_float(RFL(q3.w));  \
    }
#define GATHER8(ii, uu)                                                          \
    _Pragma("unroll") for (int k = 0; k < 8; k++) uu[k] =                        \
        *(const unsigned int*)(xs + (size_t)ii[k] * XSS + f0);

    int ja = s0a, jb = s0b;
    // joint full batches: 2 independent chains in flight
    while (ja + 8 <= s1a && jb + 8 <= s1b) {
        int ia[8], ib[8];
        float aa[8], ab[8];
        LOADMETA(ja, ia, aa)
        LOADMETA(jb, ib, ab)
        unsigned int ua[8], ub[8];
        GATHER8(ia, ua)
        GATHER8(ib, ub)
#pragma unroll
        for (int k = 0; k < 8; k++) EDGE2(ua[k], aa[k], dena, numa)
#pragma unroll
        for (int k = 0; k < 8; k++) EDGE2(ub[k], ab[k], denb, numb)
        ja += 8;
        jb += 8;
    }
    // drain whichever node still has full batches (at most one loop runs)
    while (ja + 8 <= s1a) {
        int ia[8];
        float aa[8];
        LOADMETA(ja, ia, aa)
        unsigned int ua[8];
        GATHER8(ia, ua)
#pragma unroll
        for (int k = 0; k < 8; k++) EDGE2(ua[k], aa[k], dena, numa)
        ja += 8;
    }
    while (jb + 8 <= s1b) {
        int ib[8];
        float ab[8];
        LOADMETA(jb, ib, ab)
        unsigned int ub[8];
        GATHER8(ib, ub)
#pragma unroll
        for (int k = 0; k < 8; k++) EDGE2(ub[k], ab[k], denb, numb)
        jb += 8;
    }
    // joint masked tails (index clamped to last valid edge; zero-degree -> row 0, mask 0)
    if (ja < s1a || jb < s1b) {
        int lasta = (s1a > s0a) ? s1a - 1 : 0;
        int lastb = (s1b > s0b) ? s1b - 1 : 0;
        int ia[8], ib[8];
        float aa[8], ab[8], ma[8], mb[8];
#pragma unroll
        for (int k = 0; k < 8; k++) {
            int jj = ja + k;
            int cl = (jj < s1a) ? jj : lasta;
            int2 p = sedge[cl];
            ia[k] = RFL(p.x);
            aa[k] = __int_as_float(RFL(p.y));
            ma[k] = (jj < s1a) ? 1.f : 0.f;
            jj = jb + k;
            cl = (jj < s1b) ? jj : lastb;
            int2 q = sedge[cl];
            ib[k] = RFL(q.x);
            ab[k] = __int_as_float(RFL(q.y));
            mb[k] = (jj < s1b) ? 1.f : 0.f;
        }
        unsigned int ua[8], ub[8];
        GATHER8(ia, ua)
        GATHER8(ib, ub)
#pragma unroll
        for (int k = 0; k < 8; k++) EDGE2M(ua[k], aa[k], ma[k], dena, numa)
#pragma unroll
        for (int k = 0; k < 8; k++) EDGE2M(ub[k], ab[k], mb[k], denb, numb)
    }
#undef EDGE2
#undef EDGE2M
#undef LOADMETA
#undef GATHER8
    float a0 = (s1a > s0a) ? (numa.x / dena.x + 1e-7f) : 0.f;
    float a1 = (s1a > s0a) ? (numa.y / dena.y + 1e-7f) : 0.f;
    float b0 = (s1b > s0b) ? (numb.x / denb.x + 1e-7f) : 0.f;
    float b1 = (s1b > s0b) ? (numb.y / denb.y + 1e-7f) : 0.f;
    unsigned int lo = f2bf(a0 + bf2f_lo(uda));
    unsigned int hi = f2bf(a1 + bf2f_hi(uda));
    *(unsigned int*)(outb + (size_t)d0 * Hh + f0) = lo | (hi << 16);
    lo = f2bf(b0 + bf2f_lo(udb));
    hi = f2bf(b1 + bf2f_hi(udb));
    *(unsigned int*)(outb + (size_t)d1 * Hh + f0) = lo | (hi << 16);
}

// ---------------- final norm + hierarchical mean-pool ----------------

#define PCHUNK 100

__global__ __launch_bounds__(128) void pool_kernel(
    const float* __restrict__ h, const int* __restrict__ batch,
    const float* __restrict__ g, const float* __restrict__ b,
    const float* __restrict__ m, const float* __restrict__ v,
    float* __restrict__ pooled, float* __restrict__ cnt) {
    int hh = threadIdx.x;
    int i0 = blockIdx.x * PCHUNK;
    int i1 = min(i0 + PCHUNK, Nn);
    if (i0 >= Nn) return;
    float gg = g[hh], bb = b[hh], mm = m[hh], inv = rsqrtf(v[hh] + 1e-5f);
    int cur = batch[i0];
    float sum = 0.f, c = 0.f;
    for (int i = i0; i < i1; i++) {
        int gid = batch[i];
        float val = fmaxf(gg * (h[(size_t)i * Hh + hh] - mm) * inv + bb, 0.f);
        if (gid != cur) {
            atomicAdd(&pooled[(size_t)cur * Hh + hh], sum);
            if (hh == 0) atomicAdd(&cnt[cur], c);
            cur = gid;
            sum = 0.f;
            c = 0.f;
        }
        sum += val;
        c += 1.f;
    }
    atomicAdd(&pooled[(size_t)cur * Hh + hh], sum);
    if (hh == 0) atomicAdd(&cnt[cur], c);
}

// ---------------- classifier ----------------

__global__ __launch_bounds__(128) void cls_kernel(const float* __restrict__ pooled,
                                                  const float* __restrict__ cnt,
                                                  const float* __restrict__ clinical,
                                                  const float* __restrict__ w,
                                                  const float* __restrict__ bias,
                                                  float* __restrict__ out) {
    int t = threadIdx.x;
    int g = t >> 1, c = t & 1;
    float inv = 1.f / fmaxf(cnt[g], 1.f);
    float s = bias[c];
    for (int j = 0; j < Hh; j++) s += pooled[g * Hh + j] * inv * w[j * NCc + c];
    for (int k = 0; k < Kk; k++) s += clinical[g * Kk + k] * w[(Hh + k) * NCc + c];
    out[g * NCc + c] = s;
}

// ---------------- launch ----------------

extern "C" void kernel_launch(void* const* d_in, const int* in_sizes, int n_in,
                              void* d_out, int out_size, void* d_ws, size_t ws_size,
                              hipStream_t stream) {
    const float* x = (const float*)d_in[0];
    const int* eidx = (const int*)d_in[1];
    const float* eattr = (const float*)d_in[2];
    const int* batch = (const int*)d_in[3];
    const float* clinical = (const float*)d_in[4];
    const float* lin_src_w = (const float*)d_in[5];
    const float* lin_src_b = (const float*)d_in[6];
    const float* lin_dst_w = (const float*)d_in[7];
    const float* lin_dst_b = (const float*)d_in[8];
    const float* edge_w = (const float*)d_in[9];
    const float* edge_b = (const float*)d_in[10];
    const float* tt = (const float*)d_in[11];
    const float* mlp_w1 = (const float*)d_in[12];
    const float* mlp_b1 = (const float*)d_in[13];
    const float* bn_g = (const float*)d_in[14];
    const float* bn_b = (const float*)d_in[15];
    const float* bn_m = (const float*)d_in[16];
    const float* bn_v = (const float*)d_in[17];
    const float* mlp_w2 = (const float*)d_in[18];
    const float* mlp_b2 = (const float*)d_in[19];
    const float* norm_g = (const float*)d_in[20];
    const float* norm_b = (const float*)d_in[21];
    const float* norm_m = (const float*)d_in[22];
    const float* norm_v = (const float*)d_in[23];
    const float* cls_w = (const float*)d_in[24];
    const float* cls_b = (const float*)d_in[25];
    float* out = (float*)d_out;

    const int* src = eidx;
    const int* dst = eidx + Ee;

    char* ws = (char*)d_ws;
    size_t off_b = 0;
    auto alloc = [&](size_t bytes) -> void* {
        void* p = ws + off_b;
        off_b += (bytes + 255) & ~(size_t)255;
        return p;
    };
    // All GEMM-touched buffers padded to MPAD rows (garbage pad rows never read).
    unsigned short* xsd = (unsigned short*)alloc((size_t)MPAD * 256 * 2);   // proj out
    unsigned short* rbuf = (unsigned short*)alloc((size_t)MPAD * Hh * 2);   // prenorm out
    unsigned short* aggout = (unsigned short*)alloc((size_t)MPAD * Hh * 2);
    unsigned short* xbf = (unsigned short*)alloc((size_t)MPAD * 256 * 2);
    float* hbuf = (float*)alloc((size_t)MPAD * Hh * 4);
    int* deg = (int*)alloc((Nn + 1) * 4);
    int* offp = (int*)alloc((Nn + 1) * 4);
    int* pos = (int*)alloc((size_t)Nn * 4);
    int* bsum = (int*)alloc(NB * 4);
    int* boff = (int*)alloc(NB * 4);
    int2* sedge = (int2*)alloc((size_t)Ee * 8);
    float* pooled = (float*)alloc((size_t)Gg * Hh * 4);
    float* cntb = (float*)alloc(Gg * 4);
    unsigned short* wt = (unsigned short*)alloc((size_t)327680 * 2);

    hipMemsetAsync(deg, 0, (Nn + 1) * 4, stream);
    hipMemsetAsync(pooled, 0, (size_t)Gg * Hh * 4, stream);
    hipMemsetAsync(cntb, 0, Gg * 4, stream);

    hist_kernel<<<(Ee + 255) / 256, 256, 0, stream>>>(dst, deg);
    bsum_kernel<<<NB, 256, 0, stream>>>(deg, bsum);
    bscan_kernel<<<1, 256, 0, stream>>>(bsum, boff, offp);
    offsets_kernel<<<NB, 256, 0, stream>>>(deg, boff, offp, pos);
    scatter_kernel<<<(Ee + 255) / 256, 256, 0, stream>>>(src, dst, eattr, pos, sedge);
    wconv_kernel<<<1280, 256, 0, stream>>>(lin_src_w, lin_dst_w, mlp_w1, mlp_w2, wt);
    xconv_kernel<<<(Nn * Cc / 8 + 255) / 256, 256, 0, stream>>>(x, xbf);

    const unsigned short* wt_proj = wt;
    const unsigned short* wt_w1 = wt + 65536;
    const unsigned short* wt_w2 = wt + 196608;

    // Fused projection: xsd[:, :128] = x@Wsrc+b, xsd[:, 128:] = x@Wdst+b
    dim3 gproj(2, MPAD / 128);
    proj_kernel<<<gproj, 256, 0, stream>>>(xbf, wt_proj, lin_src_b, lin_dst_b, xsd);

    for (int l = 0; l < Ll; l++) {
        if (l == 0) {
            agg_kernel<256><<<Nn / 8, 256, 0, stream>>>(xsd, xsd + 128, 256, sedge, offp,
                                                        edge_w + l * Hh, edge_b + l * Hh,
                                                        tt + l, aggout);
        } else {
            agg_kernel<128><<<Nn / 8, 256, 0, stream>>>(rbuf, rbuf, Hh, sedge, offp,
                                                        edge_w + l * Hh, edge_b + l * Hh,
                                                        tt + l, aggout);
        }
        const float* png = (l < Ll - 1) ? (norm_g + (l + 1) * Hh) : nullptr;
        const float* pnb = (l < Ll - 1) ? (norm_b + (l + 1) * Hh) : nullptr;
        const float* pnm = (l < Ll - 1) ? (norm_m + (l + 1) * Hh) : nullptr;
        const float* pnv = (l < Ll - 1) ? (norm_v + (l + 1) * Hh) : nullptr;
        mlp_kernel<<<MPAD / 64, 256, 0, stream>>>(
            aggout, wt_w1 + (size_t)l * 32768, wt_w2 + (size_t)l * 32768,
            mlp_b1 + l * 2 * Hh, bn_g + l * 2 * Hh, bn_b + l * 2 * Hh,
            bn_m + l * 2 * Hh, bn_v + l * 2 * Hh, mlp_b2 + l * Hh,
            png, pnb, pnm, pnv, hbuf, rbuf, (l == 0) ? 0 : 1);
    }

    pool_kernel<<<(Nn + PCHUNK - 1) / PCHUNK, 128, 0, stream>>>(hbuf, batch, norm_g, norm_b,
                                                                norm_m, norm_v, pooled, cntb);
    cls_kernel<<<1, 128, 0, stream>>>(pooled, cntb, clinical, cls_w, cls_b, out);
}

// Round 13
// 495.451 us; speedup vs baseline: 1.0659x; 1.0659x over previous
//
#include <hip/hip_runtime.h>
#include <math.h>

// Problem constants (from reference)
#define Nn 50000
#define MPAD 50048  // Nn padded to multiple of 128 (GEMM row tiles, no guards)
#define Ee 500000
#define Cc 256
#define Hh 128
#define Ll 4
#define Gg 64
#define Kk 8
#define NCc 2

#define NB 196  // ceil(Nn/256)

typedef __attribute__((ext_vector_type(8))) short short8;
typedef __attribute__((ext_vector_type(4))) float f32x4;
typedef __attribute__((ext_vector_type(2))) float f32x2;

#define RFL __builtin_amdgcn_readfirstlane

__device__ __forceinline__ unsigned short f2bf(float f) {
    union { float f; unsigned int u; } v;
    v.f = f;
    unsigned int u = v.u;
    return (unsigned short)((u + 0x7FFFu + ((u >> 16) & 1u)) >> 16);
}
__device__ __forceinline__ float bf2f(unsigned short s) {
    union { float f; unsigned int u; } v;
    v.u = ((unsigned int)s) << 16;
    return v.f;
}
__device__ __forceinline__ float bf2f_lo(unsigned int u) {
    union { float f; unsigned int u; } v;
    v.u = u << 16;
    return v.f;
}
__device__ __forceinline__ float bf2f_hi(unsigned int u) {
    union { float f; unsigned int u; } v;
    v.u = u & 0xffff0000u;
    return v.f;
}

// ---------------- CSR build ----------------

__global__ void hist_kernel(const int* __restrict__ dst, int* __restrict__ deg) {
    int e = blockIdx.x * 256 + threadIdx.x;
    if (e < Ee) atomicAdd(&deg[dst[e]], 1);
}

__global__ __launch_bounds__(256) void bsum_kernel(const int* __restrict__ deg,
                                                   int* __restrict__ bsum) {
    __shared__ int ws[4];
    int t = threadIdx.x;
    int i = blockIdx.x * 256 + t;
    int v = (i < Nn) ? deg[i] : 0;
#pragma unroll
    for (int o = 32; o; o >>= 1) v += __shfl_down(v, o, 64);
    if ((t & 63) == 0) ws[t >> 6] = v;
    __syncthreads();
    if (t == 0) bsum[blockIdx.x] = ws[0] + ws[1] + ws[2] + ws[3];
}

__global__ __launch_bounds__(256) void bscan_kernel(const int* __restrict__ bsum,
                                                    int* __restrict__ boff,
                                                    int* __restrict__ off) {
    __shared__ int sc[256];
    int t = threadIdx.x;
    int v = (t < NB) ? bsum[t] : 0;
    sc[t] = v;
    __syncthreads();
    for (int o = 1; o < 256; o <<= 1) {
        int u = (t >= o) ? sc[t - o] : 0;
        __syncthreads();
        sc[t] += u;
        __syncthreads();
    }
    if (t < NB) boff[t] = sc[t] - v;  // exclusive
    if (t == NB - 1) off[Nn] = sc[t];
}

__global__ __launch_bounds__(256) void offsets_kernel(const int* __restrict__ deg,
                                                      const int* __restrict__ boff,
                                                      int* __restrict__ off,
                                                      int* __restrict__ pos) {
    __shared__ int sc[256];
    int t = threadIdx.x;
    int i = blockIdx.x * 256 + t;
    int v = (i < Nn) ? deg[i] : 0;
    sc[t] = v;
    __syncthreads();
    for (int o = 1; o < 256; o <<= 1) {
        int u = (t >= o) ? sc[t - o] : 0;
        __syncthreads();
        sc[t] += u;
        __syncthreads();
    }
    int excl = sc[t] - v + boff[blockIdx.x];
    if (i < Nn) {
        off[i] = excl;
        pos[i] = excl;
    }
}

__global__ void scatter_kernel(const int* __restrict__ src, const int* __restrict__ dst,
                               const float* __restrict__ attr, int* __restrict__ pos,
                               int2* __restrict__ sedge) {
    int e = blockIdx.x * 256 + threadIdx.x;
    if (e < Ee) {
        int d = dst[e];
        int p = atomicAdd(&pos[d], 1);
        sedge[p] = make_int2(src[e], __float_as_int(attr[e]));
    }
}

// ---------------- weight convert + transpose to bf16 [N][K] ----------------
// wt layout: [0, 65536)            proj  [256 n][256 k]  (n<128: lin_src col, else lin_dst)
//            [65536, 196608)       w1[l] [256 n][128 k]
//            [196608, 327680)      w2[l] [128 n][256 k]

__global__ void wconv_kernel(const float* __restrict__ lin_src_w,
                             const float* __restrict__ lin_dst_w,
                             const float* __restrict__ mlp_w1,
                             const float* __restrict__ mlp_w2,
                             unsigned short* __restrict__ wt) {
    int idx = blockIdx.x * 256 + threadIdx.x;
    if (idx >= 327680) return;
    float val;
    if (idx < 65536) {
        int n = idx >> 8, k = idx & 255;
        val = (n < 128) ? lin_src_w[k * 128 + n] : lin_dst_w[k * 128 + (n - 128)];
    } else if (idx < 196608) {
        int r = idx - 65536;
        int l = r >> 15, e = r & 32767;
        int n = e >> 7, k = e & 127;
        val = mlp_w1[(size_t)l * 32768 + k * 256 + n];
    } else {
        int r = idx - 196608;
        int l = r >> 15, e = r & 32767;
        int n = e >> 8, k = e & 255;
        val = mlp_w2[(size_t)l * 32768 + k * 128 + n];
    }
    wt[idx] = f2bf(val);
}

// ---------------- x fp32 -> bf16 (one-time, vectorized) ----------------

__global__ __launch_bounds__(256) void xconv_kernel(const float* __restrict__ x,
                                                    unsigned short* __restrict__ xbf) {
    int idx = blockIdx.x * 256 + threadIdx.x;  // 8 elems per thread
    if (idx >= (Nn * Cc) / 8) return;
    const float4* p = (const float4*)(x) + (size_t)idx * 2;
    float4 v0 = p[0], v1 = p[1];
    unsigned short t[8];
    t[0] = f2bf(v0.x); t[1] = f2bf(v0.y); t[2] = f2bf(v0.z); t[3] = f2bf(v0.w);
    t[4] = f2bf(v1.x); t[5] = f2bf(v1.y); t[6] = f2bf(v1.z); t[7] = f2bf(v1.w);
    *(short8*)(xbf + (size_t)idx * 8) = *(short8*)t;
}

#define GLOAD16(gp, lp)                                                                       \
    __builtin_amdgcn_global_load_lds(                                                         \
        (const __attribute__((address_space(1))) unsigned int*)(gp),                          \
        (__attribute__((address_space(3))) unsigned int*)(lp), 16, 0, 0)

// ---------------- projection GEMM: xsd = x @ [Wsrc|Wdst] + [bsrc|bdst] ----------------
// 128x128 tile, BK=32, 4 waves, depth-2 prefetch (3 LDS buffers, counted vmcnt).
// Epilogue staged through LDS -> coalesced short8 stores.

__global__ __launch_bounds__(256) void proj_kernel(
    const unsigned short* __restrict__ A, const unsigned short* __restrict__ Bt,
    const float* __restrict__ bias, const float* __restrict__ bias2,
    unsigned short* __restrict__ Cout) {
    __shared__ __align__(16) unsigned short SH[24576];  // 48KB: 3xA(8KB) + 3xB(8KB); C reuse
    int tid = threadIdx.x;
    int wave = tid >> 6, lane = tid & 63;
    int wr = wave >> 1, wc = wave & 1;
    int lrow = lane & 15, quad = lane >> 4;
    int m0 = blockIdx.y * 128, n0 = blockIdx.x * 128;
    const int K = 256;

    const unsigned short* ag0 = A + (size_t)(m0 + (tid >> 2)) * K + (tid & 3) * 8;
    const unsigned short* ag1 = A + (size_t)(m0 + 64 + (tid >> 2)) * K + (tid & 3) * 8;
    const unsigned short* bg0 = Bt + (size_t)(n0 + (tid >> 2)) * K + (tid & 3) * 8;
    const unsigned short* bg1 = Bt + (size_t)(n0 + 64 + (tid >> 2)) * K + (tid & 3) * 8;

    f32x4 acc[4][4];
#pragma unroll
    for (int i = 0; i < 4; i++)
#pragma unroll
        for (int j = 0; j < 4; j++) acc[i][j] = (f32x4){0.f, 0.f, 0.f, 0.f};

    auto stage = [&](int buf, int koff) {
        GLOAD16(ag0 + koff, SH + buf * 4096 + wave * 512);
        GLOAD16(ag1 + koff, SH + buf * 4096 + 2048 + wave * 512);
        GLOAD16(bg0 + koff, SH + 12288 + buf * 4096 + wave * 512);
        GLOAD16(bg1 + koff, SH + 12288 + buf * 4096 + 2048 + wave * 512);
    };

    const int ntiles = 8;
    stage(0, 0);
    stage(1, 32);
    for (int t = 0; t < ntiles; ++t) {
        if (t + 1 < ntiles) {
            asm volatile("s_waitcnt vmcnt(4)\n\ts_barrier" ::: "memory");
        } else {
            asm volatile("s_waitcnt vmcnt(0)\n\ts_barrier" ::: "memory");
        }
        if (t + 2 < ntiles) stage((t + 2) % 3, (t + 2) * 32);
        int cur = t % 3;
        const unsigned short* As = SH + cur * 4096;
        const unsigned short* Bs = SH + 12288 + cur * 4096;
        short8 af[4], bfr[4];
#pragma unroll
        for (int mt = 0; mt < 4; mt++)
            af[mt] = *(const short8*)&As[(wr * 64 + mt * 16 + lrow) * 32 + quad * 8];
#pragma unroll
        for (int nf = 0; nf < 4; nf++)
            bfr[nf] = *(const short8*)&Bs[(wc * 64 + nf * 16 + lrow) * 32 + quad * 8];
#pragma unroll
        for (int mt = 0; mt < 4; mt++)
#pragma unroll
            for (int nf = 0; nf < 4; nf++)
                acc[mt][nf] = __builtin_amdgcn_mfma_f32_16x16x32_bf16(af[mt], bfr[nf],
                                                                     acc[mt][nf], 0, 0, 0);
    }

    __syncthreads();  // all frag reads done; reuse SH for C tile
    unsigned short* Cl = SH;  // [128][128] bf16 = 32KB
#pragma unroll
    for (int nf = 0; nf < 4; nf++) {
        int gc = n0 + wc * 64 + nf * 16 + lrow;
        float bs = (gc >= 128) ? bias2[gc - 128] : bias[gc];
        int col = wc * 64 + nf * 16 + lrow;
#pragma unroll
        for (int mt = 0; mt < 4; mt++)
#pragma unroll
            for (int r = 0; r < 4; r++)
                Cl[(wr * 64 + mt * 16 + quad * 4 + r) * 128 + col] = f2bf(acc[mt][nf][r] + bs);
    }
    __syncthreads();
#pragma unroll
    for (int p = 0; p < 8; p++) {
        int vid = p * 256 + tid;
        int row = vid >> 4, cg = (vid & 15) * 8;
        short8 v = *(const short8*)&Cl[row * 128 + cg];
        *(short8*)(Cout + (size_t)(m0 + row) * 256 + n0 + cg) = v;
    }
}

// ---------------- fused per-layer MLP: hbuf (+)= agg @ W1 -> BN -> ReLU -> @ W2 + b2,
//                  plus next-layer prenorm rbuf = bf16(relu(BN_pn(hbuf))) ----------------
// LDS-staged dbuf K-loops (round-10 version, measured ~29us).  Round-12 lesson:
// register-direct A/B loads regressed to 42us -- global_load_lds's ASYNC staging
// (overlapping tile t compute with t+1 loads) is the win, not LDS locality.

__global__ __launch_bounds__(256) void mlp_kernel(
    const unsigned short* __restrict__ A,    // aggout [MPAD][128] bf16
    const unsigned short* __restrict__ W1,   // [256 n][128 k] bf16
    const unsigned short* __restrict__ W2,   // [128 n][256 k] bf16
    const float* __restrict__ b1, const float* __restrict__ bn_g,
    const float* __restrict__ bn_b, const float* __restrict__ bn_m,
    const float* __restrict__ bn_v, const float* __restrict__ b2,
    const float* __restrict__ pn_g, const float* __restrict__ pn_b,
    const float* __restrict__ pn_m, const float* __restrict__ pn_v,
    float* __restrict__ hbuf, unsigned short* __restrict__ rbuf, int rmw) {
    __shared__ __align__(16) unsigned short S[20480];    // 40KB: A1 dbuf 2x4KB @0, B1 dbuf 2x16KB @8KB
    __shared__ __align__(16) unsigned short Hm[64 * 264];  // hmid, padded rows (16B-aligned)

    int tid = threadIdx.x;
    int wave = tid >> 6, lane = tid & 63;
    int lrow = lane & 15, quad = lane >> 4;
    int m0 = blockIdx.x * 64;

    // ---- phase 1: Hm = relu(BN(A[m0:m0+64] @ W1 + b1))  (64x256) ----
    const unsigned short* ag = A + (size_t)(m0 + (tid >> 2)) * 128 + (tid & 3) * 8;
    const unsigned short* bg = W1 + (size_t)(tid >> 2) * 128 + (tid & 3) * 8;

    f32x4 acc1[4][4];
#pragma unroll
    for (int i = 0; i < 4; i++)
#pragma unroll
        for (int j = 0; j < 4; j++) acc1[i][j] = (f32x4){0.f, 0.f, 0.f, 0.f};

    auto stage1 = [&](int buf, int k0) {
        GLOAD16(ag + k0, S + buf * 2048 + wave * 512);
#pragma unroll
        for (int c = 0; c < 4; c++)
            GLOAD16(bg + (size_t)c * 64 * 128 + k0,
                    S + 4096 + buf * 8192 + c * 2048 + wave * 512);
    };

    stage1(0, 0);
    __syncthreads();
    for (int t = 0; t < 4; ++t) {
        if (t + 1 < 4) stage1((t + 1) & 1, (t + 1) * 32);
        int cur = t & 1;
        const unsigned short* A1s = S + cur * 2048;
        const unsigned short* B1s = S + 4096 + cur * 8192;
        short8 af[4], bfr[4];
#pragma unroll
        for (int mt = 0; mt < 4; mt++)
            af[mt] = *(const short8*)&A1s[(mt * 16 + lrow) * 32 + quad * 8];
#pragma unroll
        for (int nf = 0; nf < 4; nf++)
            bfr[nf] = *(const short8*)&B1s[(wave * 64 + nf * 16 + lrow) * 32 + quad * 8];
#pragma unroll
        for (int mt = 0; mt < 4; mt++)
#pragma unroll
            for (int nf = 0; nf < 4; nf++)
                acc1[mt][nf] = __builtin_amdgcn_mfma_f32_16x16x32_bf16(af[mt], bfr[nf],
                                                                      acc1[mt][nf], 0, 0, 0);
        __syncthreads();
    }

    // epilogue 1 -> Hm (LDS only)
#pragma unroll
    for (int nf = 0; nf < 4; nf++) {
        int gc = wave * 64 + nf * 16 + lrow;
        float bs = b1[gc];
        float g = bn_g[gc], bb = bn_b[gc], mm = bn_m[gc];
        float inv = rsqrtf(bn_v[gc] + 1e-5f);
#pragma unroll
        for (int mt = 0; mt < 4; mt++)
#pragma unroll
            for (int r = 0; r < 4; r++) {
                float v = acc1[mt][nf][r] + bs;
                v = fmaxf(g * (v - mm) * inv + bb, 0.f);
                Hm[(mt * 16 + quad * 4 + r) * 264 + gc] = f2bf(v);
            }
    }
    __syncthreads();  // Hm complete; phase-1 staging region free

    // ---- phase 2: C2 = Hm @ W2 + b2  (64x128) ----
    const unsigned short* b2g0 = W2 + (size_t)(tid >> 2) * 256 + (tid & 3) * 8;
    const unsigned short* b2g1 = W2 + (size_t)(64 + (tid >> 2)) * 256 + (tid & 3) * 8;

    f32x4 acc2[4][2];
#pragma unroll
    for (int i = 0; i < 4; i++)
#pragma unroll
        for (int j = 0; j < 2; j++) acc2[i][j] = (f32x4){0.f, 0.f, 0.f, 0.f};

    auto stage2 = [&](int buf, int k0) {
        GLOAD16(b2g0 + k0, S + buf * 4096 + wave * 512);
        GLOAD16(b2g1 + k0, S + buf * 4096 + 2048 + wave * 512);
    };

    stage2(0, 0);
    __syncthreads();
    for (int t = 0; t < 8; ++t) {
        if (t + 1 < 8) stage2((t + 1) & 1, (t + 1) * 32);
        int cur = t & 1;
        const unsigned short* B2s = S + cur * 4096;
        short8 af[4], bfr[2];
#pragma unroll
        for (int mt = 0; mt < 4; mt++)
            af[mt] = *(const short8*)&Hm[(mt * 16 + lrow) * 264 + t * 32 + quad * 8];
#pragma unroll
        for (int nf = 0; nf < 2; nf++)
            bfr[nf] = *(const short8*)&B2s[(wave * 32 + nf * 16 + lrow) * 32 + quad * 8];
#pragma unroll
        for (int mt = 0; mt < 4; mt++)
#pragma unroll
            for (int nf = 0; nf < 2; nf++)
                acc2[mt][nf] = __builtin_amdgcn_mfma_f32_16x16x32_bf16(af[mt], bfr[nf],
                                                                      acc2[mt][nf], 0, 0, 0);
        __syncthreads();
    }

    // epilogue 2: stage fp32 C2 in LDS (over staging region), then coalesced writeback
    float* C2 = (float*)S;  // [64][128] fp32 = 32KB
#pragma unroll
    for (int nf = 0; nf < 2; nf++) {
        int gc = wave * 32 + nf * 16 + lrow;
        float bs = b2[gc];
#pragma unroll
        for (int mt = 0; mt < 4; mt++)
#pragma unroll
            for (int r = 0; r < 4; r++)
                C2[(mt * 16 + quad * 4 + r) * 128 + gc] = acc2[mt][nf][r] + bs;
    }
    __syncthreads();
#pragma unroll
    for (int p = 0; p < 8; p++) {
        int vid = p * 256 + tid;
        int row = vid >> 5, c4 = (vid & 31) * 4;
        f32x4 v = *(const f32x4*)&C2[row * 128 + c4];
        float* hp = hbuf + (size_t)(m0 + row) * 128 + c4;
        if (rmw) v += *(const f32x4*)hp;
        *(f32x4*)hp = v;
        if (pn_g) {
            f32x4 pg = *(const f32x4*)&pn_g[c4];
            f32x4 pb = *(const f32x4*)&pn_b[c4];
            f32x4 pm = *(const f32x4*)&pn_m[c4];
            f32x4 pv = *(const f32x4*)&pn_v[c4];
            float r0 = fmaxf(pg[0] * (v[0] - pm[0]) * rsqrtf(pv[0] + 1e-5f) + pb[0], 0.f);
            float r1 = fmaxf(pg[1] * (v[1] - pm[1]) * rsqrtf(pv[1] + 1e-5f) + pb[1], 0.f);
            float r2 = fmaxf(pg[2] * (v[2] - pm[2]) * rsqrtf(pv[2] + 1e-5f) + pb[2], 0.f);
            float r3 = fmaxf(pg[3] * (v[3] - pm[3]) * rsqrtf(pv[3] + 1e-5f) + pb[3], 0.f);
            unsigned int w0 = (unsigned int)f2bf(r0) | ((unsigned int)f2bf(r1) << 16);
            unsigned int w1 = (unsigned int)f2bf(r2) | ((unsigned int)f2bf(r3) << 16);
            uint2 pk = make_uint2(w0, w1);
            *(uint2*)(rbuf + (size_t)(m0 + row) * 128 + c4) = pk;
        }
    }
}

// ---------------- Fused GENConv aggregation (2 nodes/wave, interleaved chains) --------
// Each wave owns nodes d0,d1; main loop keeps both nodes' gather chains in flight
// (round 11/12: -4us/dispatch vs 1 node/wave).  All wave-uniform control scalarized
// via readfirstlane (round-10 win).  Per-edge +1e-7 folded into the final quotient.

template <int XSS>
__global__ __launch_bounds__(256) void agg_kernel(
    const unsigned short* __restrict__ xs,
    const unsigned short* __restrict__ xd, int xds,
    const int2* __restrict__ sedge, const int* __restrict__ off,
    const float* __restrict__ ew, const float* __restrict__ eb,
    const float* __restrict__ tptr, unsigned short* __restrict__ outb) {
    int wave = threadIdx.x >> 6;
    int lane = threadIdx.x & 63;
    int d0 = blockIdx.x * 8 + wave * 2;  // Nn % 8 == 0, d0,d1 always < Nn
    int d1 = d0 + 1;
    int f0 = lane * 2;
    unsigned int uda = *(const unsigned int*)(xd + (size_t)d0 * xds + f0);
    unsigned int udb = *(const unsigned int*)(xd + (size_t)d1 * xds + f0);
    f32x2 wv = *(const f32x2*)(ew + f0);
    f32x2 bv = *(const f32x2*)(eb + f0);
    float c = tptr[0] * 1.44269504088896f;
    const f32x2 zz = {0.f, 0.f};
    int s0a = RFL(off[d0]), s1a = RFL(off[d0 + 1]);
    int s0b = RFL(off[d1]), s1b = RFL(off[d1 + 1]);
    f32x2 dena = {0.f, 0.f}, numa = {0.f, 0.f};
    f32x2 denb = {0.f, 0.f}, numb = {0.f, 0.f};

#define EDGE2(u, av, den, num)                                      \
    {                                                               \
        f32x2 xv = {bf2f_lo(u), bf2f_hi(u)};                        \
        f32x2 m = __builtin_elementwise_max(xv + bv + (av)*wv, zz); \
        f32x2 e;                                                    \
        e.x = __builtin_amdgcn_exp2f(m.x * c);                      \
        e.y = __builtin_amdgcn_exp2f(m.y * c);                      \
        den += e;                                                   \
        num += m * e;                                               \
    }
#define EDGE2M(u, av, mk, den, num)                                 \
    {                                                               \
        f32x2 xv = {bf2f_lo(u), bf2f_hi(u)};                        \
        f32x2 m = __builtin_elementwise_max(xv + bv + (av)*wv, zz); \
        f32x2 e;                                                    \
        e.x = __builtin_amdgcn_exp2f(m.x * c) * (mk);               \
        e.y = __builtin_amdgcn_exp2f(m.y * c) * (mk);               \
        den += e;                                                   \
        num += m * e;                                               \
    }
#define LOADMETA(jv, ii, aa)                                   \
    {                                                          \
        int4 q0 = *(const int4*)(sedge + (jv));                \
        int4 q1 = *(const int4*)(sedge + (jv) + 2);            \
        int4 q2 = *(const int4*)(sedge + (jv) + 4);            \
        int4 q3 = *(const int4*)(sedge + (jv) + 6);            \
        ii[0] = RFL(q0.x); aa[0] = __int_as_float(RFL(q0.y));  \
        ii[1] = RFL(q0.z); aa[1] = __int_as_float(RFL(q0.w));  \
        ii[2] = RFL(q1.x); aa[2] = __int_as_float(RFL(q1.y));  \
        ii[3] = RFL(q1.z); aa[3] = __int_as_float(RFL(q1.w));  \
        ii[4] = RFL(q2.x); aa[4] = __int_as_float(RFL(q2.y));  \
        ii[5] = RFL(q2.z); aa[5] = __int_as_float(RFL(q2.w));  \
        ii[6] = RFL(q3.x); aa[6] = __int_as_float(RFL(q3.y));  \
        ii[7] = RFL(q3.z); aa[7] = __int_as_float(RFL(q3.w));  \
    }
#define GATHER8(ii, uu)                                                          \
    _Pragma("unroll") for (int k = 0; k < 8; k++) uu[k] =                        \
        *(const unsigned int*)(xs + (size_t)ii[k] * XSS + f0);

    int ja = s0a, jb = s0b;
    // joint full batches: 2 independent chains in flight
    while (ja + 8 <= s1a && jb + 8 <= s1b) {
        int ia[8], ib[8];
        float aa[8], ab[8];
        LOADMETA(ja, ia, aa)
        LOADMETA(jb, ib, ab)
        unsigned int ua[8], ub[8];
        GATHER8(ia, ua)
        GATHER8(ib, ub)
#pragma unroll
        for (int k = 0; k < 8; k++) EDGE2(ua[k], aa[k], dena, numa)
#pragma unroll
        for (int k = 0; k < 8; k++) EDGE2(ub[k], ab[k], denb, numb)
        ja += 8;
        jb += 8;
    }
    // drain whichever node still has full batches (at most one loop runs)
    while (ja + 8 <= s1a) {
        int ia[8];
        float aa[8];
        LOADMETA(ja, ia, aa)
        unsigned int ua[8];
        GATHER8(ia, ua)
#pragma unroll
        for (int k = 0; k < 8; k++) EDGE2(ua[k], aa[k], dena, numa)
        ja += 8;
    }
    while (jb + 8 <= s1b) {
        int ib[8];
        float ab[8];
        LOADMETA(jb, ib, ab)
        unsigned int ub[8];
        GATHER8(ib, ub)
#pragma unroll
        for (int k = 0; k < 8; k++) EDGE2(ub[k], ab[k], denb, numb)
        jb += 8;
    }
    // joint masked tails (index clamped to last valid edge; zero-degree -> row 0, mask 0)
    if (ja < s1a || jb < s1b) {
        int lasta = (s1a > s0a) ? s1a - 1 : 0;
        int lastb = (s1b > s0b) ? s1b - 1 : 0;
        int ia[8], ib[8];
        float aa[8], ab[8], ma[8], mb[8];
#pragma unroll
        for (int k = 0; k < 8; k++) {
            int jj = ja + k;
            int cl = (jj < s1a) ? jj : lasta;
            int2 p = sedge[cl];
            ia[k] = RFL(p.x);
            aa[k] = __int_as_float(RFL(p.y));
            ma[k] = (jj < s1a) ? 1.f : 0.f;
            jj = jb + k;
            cl = (jj < s1b) ? jj : lastb;
            int2 q = sedge[cl];
            ib[k] = RFL(q.x);
            ab[k] = __int_as_float(RFL(q.y));
            mb[k] = (jj < s1b) ? 1.f : 0.f;
        }
        unsigned int ua[8], ub[8];
        GATHER8(ia, ua)
        GATHER8(ib, ub)
#pragma unroll
        for (int k = 0; k < 8; k++) EDGE2M(ua[k], aa[k], ma[k], dena, numa)
#pragma unroll
        for (int k = 0; k < 8; k++) EDGE2M(ub[k], ab[k], mb[k], denb, numb)
    }
#undef EDGE2
#undef EDGE2M
#undef LOADMETA
#undef GATHER8
    float a0 = (s1a > s0a) ? (numa.x / dena.x + 1e-7f) : 0.f;
    float a1 = (s1a > s0a) ? (numa.y / dena.y + 1e-7f) : 0.f;
    float b0 = (s1b > s0b) ? (numb.x / denb.x + 1e-7f) : 0.f;
    float b1 = (s1b > s0b) ? (numb.y / denb.y + 1e-7f) : 0.f;
    unsigned int lo = f2bf(a0 + bf2f_lo(uda));
    unsigned int hi = f2bf(a1 + bf2f_hi(uda));
    *(unsigned int*)(outb + (size_t)d0 * Hh + f0) = lo | (hi << 16);
    lo = f2bf(b0 + bf2f_lo(udb));
    hi = f2bf(b1 + bf2f_hi(udb));
    *(unsigned int*)(outb + (size_t)d1 * Hh + f0) = lo | (hi << 16);
}

// ---------------- final norm + hierarchical mean-pool ----------------

#define PCHUNK 100

__global__ __launch_bounds__(128) void pool_kernel(
    const float* __restrict__ h, const int* __restrict__ batch,
    const float* __restrict__ g, const float* __restrict__ b,
    const float* __restrict__ m, const float* __restrict__ v,
    float* __restrict__ pooled, float* __restrict__ cnt) {
    int hh = threadIdx.x;
    int i0 = blockIdx.x * PCHUNK;
    int i1 = min(i0 + PCHUNK, Nn);
    if (i0 >= Nn) return;
    float gg = g[hh], bb = b[hh], mm = m[hh], inv = rsqrtf(v[hh] + 1e-5f);
    int cur = batch[i0];
    float sum = 0.f, c = 0.f;
    for (int i = i0; i < i1; i++) {
        int gid = batch[i];
        float val = fmaxf(gg * (h[(size_t)i * Hh + hh] - mm) * inv + bb, 0.f);
        if (gid != cur) {
            atomicAdd(&pooled[(size_t)cur * Hh + hh], sum);
            if (hh == 0) atomicAdd(&cnt[cur], c);
            cur = gid;
            sum = 0.f;
            c = 0.f;
        }
        sum += val;
        c += 1.f;
    }
    atomicAdd(&pooled[(size_t)cur * Hh + hh], sum);
    if (hh == 0) atomicAdd(&cnt[cur], c);
}

// ---------------- classifier ----------------

__global__ __launch_bounds__(128) void cls_kernel(const float* __restrict__ pooled,
                                                  const float* __restrict__ cnt,
                                                  const float* __restrict__ clinical,
                                                  const float* __restrict__ w,
                                                  const float* __restrict__ bias,
                                                  float* __restrict__ out) {
    int t = threadIdx.x;
    int g = t >> 1, c = t & 1;
    float inv = 1.f / fmaxf(cnt[g], 1.f);
    float s = bias[c];
    for (int j = 0; j < Hh; j++) s += pooled[g * Hh + j] * inv * w[j * NCc + c];
    for (int k = 0; k < Kk; k++) s += clinical[g * Kk + k] * w[(Hh + k) * NCc + c];
    out[g * NCc + c] = s;
}

// ---------------- launch ----------------

extern "C" void kernel_launch(void* const* d_in, const int* in_sizes, int n_in,
                              void* d_out, int out_size, void* d_ws, size_t ws_size,
                              hipStream_t stream) {
    const float* x = (const float*)d_in[0];
    const int* eidx = (const int*)d_in[1];
    const float* eattr = (const float*)d_in[2];
    const int* batch = (const int*)d_in[3];
    const float* clinical = (const float*)d_in[4];
    const float* lin_src_w = (const float*)d_in[5];
    const float* lin_src_b = (const float*)d_in[6];
    const float* lin_dst_w = (const float*)d_in[7];
    const float* lin_dst_b = (const float*)d_in[8];
    const float* edge_w = (const float*)d_in[9];
    const float* edge_b = (const float*)d_in[10];
    const float* tt = (const float*)d_in[11];
    const float* mlp_w1 = (const float*)d_in[12];
    const float* mlp_b1 = (const float*)d_in[13];
    const float* bn_g = (const float*)d_in[14];
    const float* bn_b = (const float*)d_in[15];
    const float* bn_m = (const float*)d_in[16];
    const float* bn_v = (const float*)d_in[17];
    const float* mlp_w2 = (const float*)d_in[18];
    const float* mlp_b2 = (const float*)d_in[19];
    const float* norm_g = (const float*)d_in[20];
    const float* norm_b = (const float*)d_in[21];
    const float* norm_m = (const float*)d_in[22];
    const float* norm_v = (const float*)d_in[23];
    const float* cls_w = (const float*)d_in[24];
    const float* cls_b = (const float*)d_in[25];
    float* out = (float*)d_out;

    const int* src = eidx;
    const int* dst = eidx + Ee;

    char* ws = (char*)d_ws;
    size_t off_b = 0;
    auto alloc = [&](size_t bytes) -> void* {
        void* p = ws + off_b;
        off_b += (bytes + 255) & ~(size_t)255;
        return p;
    };
    // All GEMM-touched buffers padded to MPAD rows (garbage pad rows never read).
    unsigned short* xsd = (unsigned short*)alloc((size_t)MPAD * 256 * 2);   // proj out
    unsigned short* rbuf = (unsigned short*)alloc((size_t)MPAD * Hh * 2);   // prenorm out
    unsigned short* aggout = (unsigned short*)alloc((size_t)MPAD * Hh * 2);
    unsigned short* xbf = (unsigned short*)alloc((size_t)MPAD * 256 * 2);
    float* hbuf = (float*)alloc((size_t)MPAD * Hh * 4);
    int* deg = (int*)alloc((Nn + 1) * 4);
    int* offp = (int*)alloc((Nn + 1) * 4);
    int* pos = (int*)alloc((size_t)Nn * 4);
    int* bsum = (int*)alloc(NB * 4);
    int* boff = (int*)alloc(NB * 4);
    int2* sedge = (int2*)alloc((size_t)Ee * 8);
    float* pooled = (float*)alloc((size_t)Gg * Hh * 4);
    float* cntb = (float*)alloc(Gg * 4);
    unsigned short* wt = (unsigned short*)alloc((size_t)327680 * 2);

    hipMemsetAsync(deg, 0, (Nn + 1) * 4, stream);
    hipMemsetAsync(pooled, 0, (size_t)Gg * Hh * 4, stream);
    hipMemsetAsync(cntb, 0, Gg * 4, stream);

    hist_kernel<<<(Ee + 255) / 256, 256, 0, stream>>>(dst, deg);
    bsum_kernel<<<NB, 256, 0, stream>>>(deg, bsum);
    bscan_kernel<<<1, 256, 0, stream>>>(bsum, boff, offp);
    offsets_kernel<<<NB, 256, 0, stream>>>(deg, boff, offp, pos);
    scatter_kernel<<<(Ee + 255) / 256, 256, 0, stream>>>(src, dst, eattr, pos, sedge);
    wconv_kernel<<<1280, 256, 0, stream>>>(lin_src_w, lin_dst_w, mlp_w1, mlp_w2, wt);
    xconv_kernel<<<(Nn * Cc / 8 + 255) / 256, 256, 0, stream>>>(x, xbf);

    const unsigned short* wt_proj = wt;
    const unsigned short* wt_w1 = wt + 65536;
    const unsigned short* wt_w2 = wt + 196608;

    // Fused projection: xsd[:, :128] = x@Wsrc+b, xsd[:, 128:] = x@Wdst+b
    dim3 gproj(2, MPAD / 128);
    proj_kernel<<<gproj, 256, 0, stream>>>(xbf, wt_proj, lin_src_b, lin_dst_b, xsd);

    for (int l = 0; l < Ll; l++) {
        if (l == 0) {
            agg_kernel<256><<<Nn / 8, 256, 0, stream>>>(xsd, xsd + 128, 256, sedge, offp,
                                                        edge_w + l * Hh, edge_b + l * Hh,
                                                        tt + l, aggout);
        } else {
            agg_kernel<128><<<Nn / 8, 256, 0, stream>>>(rbuf, rbuf, Hh, sedge, offp,
                                                        edge_w + l * Hh, edge_b + l * Hh,
                                                        tt + l, aggout);
        }
        const float* png = (l < Ll - 1) ? (norm_g + (l + 1) * Hh) : nullptr;
        const float* pnb = (l < Ll - 1) ? (norm_b + (l + 1) * Hh) : nullptr;
        const float* pnm = (l < Ll - 1) ? (norm_m + (l + 1) * Hh) : nullptr;
        const float* pnv = (l < Ll - 1) ? (norm_v + (l + 1) * Hh) : nullptr;
        mlp_kernel<<<MPAD / 64, 256, 0, stream>>>(
            aggout, wt_w1 + (size_t)l * 32768, wt_w2 + (size_t)l * 32768,
            mlp_b1 + l * 2 * Hh, bn_g + l * 2 * Hh, bn_b + l * 2 * Hh,
            bn_m + l * 2 * Hh, bn_v + l * 2 * Hh, mlp_b2 + l * Hh,
            png, pnb, pnm, pnv, hbuf, rbuf, (l == 0) ? 0 : 1);
    }

    pool_kernel<<<(Nn + PCHUNK - 1) / PCHUNK, 128, 0, stream>>>(hbuf, batch, norm_g, norm_b,
                                                                norm_m, norm_v, pooled, cntb);
    cls_kernel<<<1, 128, 0, stream>>>(pooled, cntb, clinical, cls_w, cls_b, out);
}

// Round 14
// 490.520 us; speedup vs baseline: 1.0766x; 1.0101x over previous
//
#include <hip/hip_runtime.h>
#include <math.h>

// Problem constants (from reference)
#define Nn 50000
#define MPAD 50048  // Nn padded to multiple of 128 (GEMM row tiles, no guards)
#define Ee 500000
#define Cc 256
#define Hh 128
#define Ll 4
#define Gg 64
#define Kk 8
#define NCc 2

#define NB 196  // ceil(Nn/256)

typedef __attribute__((ext_vector_type(8))) short short8;
typedef __attribute__((ext_vector_type(4))) float f32x4;
typedef __attribute__((ext_vector_type(2))) float f32x2;

#define RFL __builtin_amdgcn_readfirstlane

__device__ __forceinline__ unsigned short f2bf(float f) {
    union { float f; unsigned int u; } v;
    v.f = f;
    unsigned int u = v.u;
    return (unsigned short)((u + 0x7FFFu + ((u >> 16) & 1u)) >> 16);
}
__device__ __forceinline__ float bf2f(unsigned short s) {
    union { float f; unsigned int u; } v;
    v.u = ((unsigned int)s) << 16;
    return v.f;
}
__device__ __forceinline__ float bf2f_lo(unsigned int u) {
    union { float f; unsigned int u; } v;
    v.u = u << 16;
    return v.f;
}
__device__ __forceinline__ float bf2f_hi(unsigned int u) {
    union { float f; unsigned int u; } v;
    v.u = u & 0xffff0000u;
    return v.f;
}

// ---------------- CSR build ----------------

__global__ void hist_kernel(const int* __restrict__ dst, int* __restrict__ deg) {
    int e = blockIdx.x * 256 + threadIdx.x;
    if (e < Ee) atomicAdd(&deg[dst[e]], 1);
}

__global__ __launch_bounds__(256) void bsum_kernel(const int* __restrict__ deg,
                                                   int* __restrict__ bsum) {
    __shared__ int ws[4];
    int t = threadIdx.x;
    int i = blockIdx.x * 256 + t;
    int v = (i < Nn) ? deg[i] : 0;
#pragma unroll
    for (int o = 32; o; o >>= 1) v += __shfl_down(v, o, 64);
    if ((t & 63) == 0) ws[t >> 6] = v;
    __syncthreads();
    if (t == 0) bsum[blockIdx.x] = ws[0] + ws[1] + ws[2] + ws[3];
}

__global__ __launch_bounds__(256) void bscan_kernel(const int* __restrict__ bsum,
                                                    int* __restrict__ boff,
                                                    int* __restrict__ off) {
    __shared__ int sc[256];
    int t = threadIdx.x;
    int v = (t < NB) ? bsum[t] : 0;
    sc[t] = v;
    __syncthreads();
    for (int o = 1; o < 256; o <<= 1) {
        int u = (t >= o) ? sc[t - o] : 0;
        __syncthreads();
        sc[t] += u;
        __syncthreads();
    }
    if (t < NB) boff[t] = sc[t] - v;  // exclusive
    if (t == NB - 1) off[Nn] = sc[t];
}

__global__ __launch_bounds__(256) void offsets_kernel(const int* __restrict__ deg,
                                                      const int* __restrict__ boff,
                                                      int* __restrict__ off,
                                                      int* __restrict__ pos) {
    __shared__ int sc[256];
    int t = threadIdx.x;
    int i = blockIdx.x * 256 + t;
    int v = (i < Nn) ? deg[i] : 0;
    sc[t] = v;
    __syncthreads();
    for (int o = 1; o < 256; o <<= 1) {
        int u = (t >= o) ? sc[t - o] : 0;
        __syncthreads();
        sc[t] += u;
        __syncthreads();
    }
    int excl = sc[t] - v + boff[blockIdx.x];
    if (i < Nn) {
        off[i] = excl;
        pos[i] = excl;
    }
}

__global__ void scatter_kernel(const int* __restrict__ src, const int* __restrict__ dst,
                               const float* __restrict__ attr, int* __restrict__ pos,
                               int2* __restrict__ sedge) {
    int e = blockIdx.x * 256 + threadIdx.x;
    if (e < Ee) {
        int d = dst[e];
        int p = atomicAdd(&pos[d], 1);
        sedge[p] = make_int2(src[e], __float_as_int(attr[e]));
    }
}

// ---------------- weight convert + transpose to bf16 [N][K] ----------------
// wt layout: [0, 65536)            proj  [256 n][256 k]  (n<128: lin_src col, else lin_dst)
//            [65536, 196608)       w1[l] [256 n][128 k]
//            [196608, 327680)      w2[l] [128 n][256 k]

__global__ void wconv_kernel(const float* __restrict__ lin_src_w,
                             const float* __restrict__ lin_dst_w,
                             const float* __restrict__ mlp_w1,
                             const float* __restrict__ mlp_w2,
                             unsigned short* __restrict__ wt) {
    int idx = blockIdx.x * 256 + threadIdx.x;
    if (idx >= 327680) return;
    float val;
    if (idx < 65536) {
        int n = idx >> 8, k = idx & 255;
        val = (n < 128) ? lin_src_w[k * 128 + n] : lin_dst_w[k * 128 + (n - 128)];
    } else if (idx < 196608) {
        int r = idx - 65536;
        int l = r >> 15, e = r & 32767;
        int n = e >> 7, k = e & 127;
        val = mlp_w1[(size_t)l * 32768 + k * 256 + n];
    } else {
        int r = idx - 196608;
        int l = r >> 15, e = r & 32767;
        int n = e >> 8, k = e & 255;
        val = mlp_w2[(size_t)l * 32768 + k * 128 + n];
    }
    wt[idx] = f2bf(val);
}

// ---------------- x fp32 -> bf16 (one-time, vectorized) ----------------

__global__ __launch_bounds__(256) void xconv_kernel(const float* __restrict__ x,
                                                    unsigned short* __restrict__ xbf) {
    int idx = blockIdx.x * 256 + threadIdx.x;  // 8 elems per thread
    if (idx >= (Nn * Cc) / 8) return;
    const float4* p = (const float4*)(x) + (size_t)idx * 2;
    float4 v0 = p[0], v1 = p[1];
    unsigned short t[8];
    t[0] = f2bf(v0.x); t[1] = f2bf(v0.y); t[2] = f2bf(v0.z); t[3] = f2bf(v0.w);
    t[4] = f2bf(v1.x); t[5] = f2bf(v1.y); t[6] = f2bf(v1.z); t[7] = f2bf(v1.w);
    *(short8*)(xbf + (size_t)idx * 8) = *(short8*)t;
}

#define GLOAD16(gp, lp)                                                                       \
    __builtin_amdgcn_global_load_lds(                                                         \
        (const __attribute__((address_space(1))) unsigned int*)(gp),                          \
        (__attribute__((address_space(3))) unsigned int*)(lp), 16, 0, 0)

// ---------------- projection GEMM: xsd = x @ [Wsrc|Wdst] + [bsrc|bdst] ----------------
// 128x128 tile, BK=32, 4 waves, depth-2 prefetch (3 LDS buffers, counted vmcnt).
// Epilogue staged through LDS -> coalesced short8 stores.

__global__ __launch_bounds__(256) void proj_kernel(
    const unsigned short* __restrict__ A, const unsigned short* __restrict__ Bt,
    const float* __restrict__ bias, const float* __restrict__ bias2,
    unsigned short* __restrict__ Cout) {
    __shared__ __align__(16) unsigned short SH[24576];  // 48KB: 3xA(8KB) + 3xB(8KB); C reuse
    int tid = threadIdx.x;
    int wave = tid >> 6, lane = tid & 63;
    int wr = wave >> 1, wc = wave & 1;
    int lrow = lane & 15, quad = lane >> 4;
    int m0 = blockIdx.y * 128, n0 = blockIdx.x * 128;
    const int K = 256;

    const unsigned short* ag0 = A + (size_t)(m0 + (tid >> 2)) * K + (tid & 3) * 8;
    const unsigned short* ag1 = A + (size_t)(m0 + 64 + (tid >> 2)) * K + (tid & 3) * 8;
    const unsigned short* bg0 = Bt + (size_t)(n0 + (tid >> 2)) * K + (tid & 3) * 8;
    const unsigned short* bg1 = Bt + (size_t)(n0 + 64 + (tid >> 2)) * K + (tid & 3) * 8;

    f32x4 acc[4][4];
#pragma unroll
    for (int i = 0; i < 4; i++)
#pragma unroll
        for (int j = 0; j < 4; j++) acc[i][j] = (f32x4){0.f, 0.f, 0.f, 0.f};

    auto stage = [&](int buf, int koff) {
        GLOAD16(ag0 + koff, SH + buf * 4096 + wave * 512);
        GLOAD16(ag1 + koff, SH + buf * 4096 + 2048 + wave * 512);
        GLOAD16(bg0 + koff, SH + 12288 + buf * 4096 + wave * 512);
        GLOAD16(bg1 + koff, SH + 12288 + buf * 4096 + 2048 + wave * 512);
    };

    const int ntiles = 8;
    stage(0, 0);
    stage(1, 32);
    for (int t = 0; t < ntiles; ++t) {
        if (t + 1 < ntiles) {
            asm volatile("s_waitcnt vmcnt(4)\n\ts_barrier" ::: "memory");
        } else {
            asm volatile("s_waitcnt vmcnt(0)\n\ts_barrier" ::: "memory");
        }
        if (t + 2 < ntiles) stage((t + 2) % 3, (t + 2) * 32);
        int cur = t % 3;
        const unsigned short* As = SH + cur * 4096;
        const unsigned short* Bs = SH + 12288 + cur * 4096;
        short8 af[4], bfr[4];
#pragma unroll
        for (int mt = 0; mt < 4; mt++)
            af[mt] = *(const short8*)&As[(wr * 64 + mt * 16 + lrow) * 32 + quad * 8];
#pragma unroll
        for (int nf = 0; nf < 4; nf++)
            bfr[nf] = *(const short8*)&Bs[(wc * 64 + nf * 16 + lrow) * 32 + quad * 8];
#pragma unroll
        for (int mt = 0; mt < 4; mt++)
#pragma unroll
            for (int nf = 0; nf < 4; nf++)
                acc[mt][nf] = __builtin_amdgcn_mfma_f32_16x16x32_bf16(af[mt], bfr[nf],
                                                                     acc[mt][nf], 0, 0, 0);
    }

    __syncthreads();  // all frag reads done; reuse SH for C tile
    unsigned short* Cl = SH;  // [128][128] bf16 = 32KB
#pragma unroll
    for (int nf = 0; nf < 4; nf++) {
        int gc = n0 + wc * 64 + nf * 16 + lrow;
        float bs = (gc >= 128) ? bias2[gc - 128] : bias[gc];
        int col = wc * 64 + nf * 16 + lrow;
#pragma unroll
        for (int mt = 0; mt < 4; mt++)
#pragma unroll
            for (int r = 0; r < 4; r++)
                Cl[(wr * 64 + mt * 16 + quad * 4 + r) * 128 + col] = f2bf(acc[mt][nf][r] + bs);
    }
    __syncthreads();
#pragma unroll
    for (int p = 0; p < 8; p++) {
        int vid = p * 256 + tid;
        int row = vid >> 4, cg = (vid & 15) * 8;
        short8 v = *(const short8*)&Cl[row * 128 + cg];
        *(short8*)(Cout + (size_t)(m0 + row) * 256 + n0 + cg) = v;
    }
}

// ---------------- fused per-layer MLP: hbuf (+)= agg @ W1 -> BN -> ReLU -> @ W2 + b2,
//                  plus next-layer prenorm rbuf = bf16(relu(BN_pn(hbuf))) ----------------
// LDS OVERLAY (round-13 fix): phase buffers are sequential-phase, so they share one
// 50,176B arena instead of 74,752B of disjoint buffers -> 3 blocks/CU (was 2).
//   [0, 40KB)       phase-1 staging: A1 dbuf 2x4KB @0, B1 dbuf 2x16KB @8KB
//   [0, 33.8KB)     Hm (overlays staging AFTER phase-1 K-loop's final barrier)
//   [33.8, 49.8KB)  B2 dbuf 2x8KB (live alongside Hm, disjoint)
//   [0, 32KB)       C2 fp32 (overlays Hm AFTER phase-2's final barrier)
// stage2(0) issued right after the phase-1 loop (staging reads complete there;
// B2 region only overlaps dead phase-1 staging) -> hides under epilogue-1.

__global__ __launch_bounds__(256) void mlp_kernel(
    const unsigned short* __restrict__ A,    // aggout [MPAD][128] bf16
    const unsigned short* __restrict__ W1,   // [256 n][128 k] bf16
    const unsigned short* __restrict__ W2,   // [128 n][256 k] bf16
    const float* __restrict__ b1, const float* __restrict__ bn_g,
    const float* __restrict__ bn_b, const float* __restrict__ bn_m,
    const float* __restrict__ bn_v, const float* __restrict__ b2,
    const float* __restrict__ pn_g, const float* __restrict__ pn_b,
    const float* __restrict__ pn_m, const float* __restrict__ pn_v,
    float* __restrict__ hbuf, unsigned short* __restrict__ rbuf, int rmw) {
    __shared__ __align__(16) unsigned short LDS_[25088];  // 50,176 B arena
    unsigned short* S = LDS_;          // phase-1 staging [0, 20480 shorts)
    unsigned short* Hm = LDS_;         // [64][264] bf16 at [0, 16896 shorts)
    unsigned short* B2 = LDS_ + 16896; // B2 dbuf [16896, 25088 shorts)

    int tid = threadIdx.x;
    int wave = tid >> 6, lane = tid & 63;
    int lrow = lane & 15, quad = lane >> 4;
    int m0 = blockIdx.x * 64;

    // ---- phase 1: Hm = relu(BN(A[m0:m0+64] @ W1 + b1))  (64x256) ----
    const unsigned short* ag = A + (size_t)(m0 + (tid >> 2)) * 128 + (tid & 3) * 8;
    const unsigned short* bg = W1 + (size_t)(tid >> 2) * 128 + (tid & 3) * 8;

    f32x4 acc1[4][4];
#pragma unroll
    for (int i = 0; i < 4; i++)
#pragma unroll
        for (int j = 0; j < 4; j++) acc1[i][j] = (f32x4){0.f, 0.f, 0.f, 0.f};

    auto stage1 = [&](int buf, int k0) {
        GLOAD16(ag + k0, S + buf * 2048 + wave * 512);
#pragma unroll
        for (int c = 0; c < 4; c++)
            GLOAD16(bg + (size_t)c * 64 * 128 + k0,
                    S + 4096 + buf * 8192 + c * 2048 + wave * 512);
    };

    stage1(0, 0);
    __syncthreads();
    for (int t = 0; t < 4; ++t) {
        if (t + 1 < 4) stage1((t + 1) & 1, (t + 1) * 32);
        int cur = t & 1;
        const unsigned short* A1s = S + cur * 2048;
        const unsigned short* B1s = S + 4096 + cur * 8192;
        short8 af[4], bfr[4];
#pragma unroll
        for (int mt = 0; mt < 4; mt++)
            af[mt] = *(const short8*)&A1s[(mt * 16 + lrow) * 32 + quad * 8];
#pragma unroll
        for (int nf = 0; nf < 4; nf++)
            bfr[nf] = *(const short8*)&B1s[(wave * 64 + nf * 16 + lrow) * 32 + quad * 8];
#pragma unroll
        for (int mt = 0; mt < 4; mt++)
#pragma unroll
            for (int nf = 0; nf < 4; nf++)
                acc1[mt][nf] = __builtin_amdgcn_mfma_f32_16x16x32_bf16(af[mt], bfr[nf],
                                                                      acc1[mt][nf], 0, 0, 0);
        __syncthreads();
    }
    // all phase-1 staging reads done (final barrier above); staging region is dead.

    // phase-2 W2 fragment sources
    const unsigned short* b2g0 = W2 + (size_t)(tid >> 2) * 256 + (tid & 3) * 8;
    const unsigned short* b2g1 = W2 + (size_t)(64 + (tid >> 2)) * 256 + (tid & 3) * 8;
    auto stage2 = [&](int buf, int k0) {
        GLOAD16(b2g0 + k0, B2 + buf * 4096 + wave * 512);
        GLOAD16(b2g1 + k0, B2 + buf * 4096 + 2048 + wave * 512);
    };
    stage2(0, 0);  // async; lands during epilogue-1 (drained by the next barrier)

    // epilogue 1 -> Hm (overlays dead staging region; writes-only until barrier)
#pragma unroll
    for (int nf = 0; nf < 4; nf++) {
        int gc = wave * 64 + nf * 16 + lrow;
        float bs = b1[gc];
        float g = bn_g[gc], bb = bn_b[gc], mm = bn_m[gc];
        float inv = rsqrtf(bn_v[gc] + 1e-5f);
#pragma unroll
        for (int mt = 0; mt < 4; mt++)
#pragma unroll
            for (int r = 0; r < 4; r++) {
                float v = acc1[mt][nf][r] + bs;
                v = fmaxf(g * (v - mm) * inv + bb, 0.f);
                Hm[(mt * 16 + quad * 4 + r) * 264 + gc] = f2bf(v);
            }
    }
    __syncthreads();  // Hm complete + stage2(0) landed (vmcnt drained at barrier)

    // ---- phase 2: C2 = Hm @ W2 + b2  (64x128) ----
    f32x4 acc2[4][2];
#pragma unroll
    for (int i = 0; i < 4; i++)
#pragma unroll
        for (int j = 0; j < 2; j++) acc2[i][j] = (f32x4){0.f, 0.f, 0.f, 0.f};

    for (int t = 0; t < 8; ++t) {
        if (t + 1 < 8) stage2((t + 1) & 1, (t + 1) * 32);
        int cur = t & 1;
        const unsigned short* B2s = B2 + cur * 4096;
        short8 af[4], bfr[2];
#pragma unroll
        for (int mt = 0; mt < 4; mt++)
            af[mt] = *(const short8*)&Hm[(mt * 16 + lrow) * 264 + t * 32 + quad * 8];
#pragma unroll
        for (int nf = 0; nf < 2; nf++)
            bfr[nf] = *(const short8*)&B2s[(wave * 32 + nf * 16 + lrow) * 32 + quad * 8];
#pragma unroll
        for (int mt = 0; mt < 4; mt++)
#pragma unroll
            for (int nf = 0; nf < 2; nf++)
                acc2[mt][nf] = __builtin_amdgcn_mfma_f32_16x16x32_bf16(af[mt], bfr[nf],
                                                                      acc2[mt][nf], 0, 0, 0);
        __syncthreads();
    }
    // all Hm/B2 reads done (final barrier above); reuse arena as fp32 C2 [64][128]

    float* C2 = (float*)LDS_;
#pragma unroll
    for (int nf = 0; nf < 2; nf++) {
        int gc = wave * 32 + nf * 16 + lrow;
        float bs = b2[gc];
#pragma unroll
        for (int mt = 0; mt < 4; mt++)
#pragma unroll
            for (int r = 0; r < 4; r++)
                C2[(mt * 16 + quad * 4 + r) * 128 + gc] = acc2[mt][nf][r] + bs;
    }
    __syncthreads();
#pragma unroll
    for (int p = 0; p < 8; p++) {
        int vid = p * 256 + tid;
        int row = vid >> 5, c4 = (vid & 31) * 4;
        f32x4 v = *(const f32x4*)&C2[row * 128 + c4];
        float* hp = hbuf + (size_t)(m0 + row) * 128 + c4;
        if (rmw) v += *(const f32x4*)hp;
        *(f32x4*)hp = v;
        if (pn_g) {
            f32x4 pg = *(const f32x4*)&pn_g[c4];
            f32x4 pb = *(const f32x4*)&pn_b[c4];
            f32x4 pm = *(const f32x4*)&pn_m[c4];
            f32x4 pv = *(const f32x4*)&pn_v[c4];
            float r0 = fmaxf(pg[0] * (v[0] - pm[0]) * rsqrtf(pv[0] + 1e-5f) + pb[0], 0.f);
            float r1 = fmaxf(pg[1] * (v[1] - pm[1]) * rsqrtf(pv[1] + 1e-5f) + pb[1], 0.f);
            float r2 = fmaxf(pg[2] * (v[2] - pm[2]) * rsqrtf(pv[2] + 1e-5f) + pb[2], 0.f);
            float r3 = fmaxf(pg[3] * (v[3] - pm[3]) * rsqrtf(pv[3] + 1e-5f) + pb[3], 0.f);
            unsigned int w0 = (unsigned int)f2bf(r0) | ((unsigned int)f2bf(r1) << 16);
            unsigned int w1 = (unsigned int)f2bf(r2) | ((unsigned int)f2bf(r3) << 16);
            uint2 pk = make_uint2(w0, w1);
            *(uint2*)(rbuf + (size_t)(m0 + row) * 128 + c4) = pk;
        }
    }
}

// ---------------- Fused GENConv aggregation (2 nodes/wave, interleaved chains) --------
// Each wave owns nodes d0,d1; main loop keeps both nodes' gather chains in flight
// (round 11/12: -4us/dispatch vs 1 node/wave).  All wave-uniform control scalarized
// via readfirstlane (round-10 win).  Per-edge +1e-7 folded into the final quotient.

template <int XSS>
__global__ __launch_bounds__(256) void agg_kernel(
    const unsigned short* __restrict__ xs,
    const unsigned short* __restrict__ xd, int xds,
    const int2* __restrict__ sedge, const int* __restrict__ off,
    const float* __restrict__ ew, const float* __restrict__ eb,
    const float* __restrict__ tptr, unsigned short* __restrict__ outb) {
    int wave = threadIdx.x >> 6;
    int lane = threadIdx.x & 63;
    int d0 = blockIdx.x * 8 + wave * 2;  // Nn % 8 == 0, d0,d1 always < Nn
    int d1 = d0 + 1;
    int f0 = lane * 2;
    unsigned int uda = *(const unsigned int*)(xd + (size_t)d0 * xds + f0);
    unsigned int udb = *(const unsigned int*)(xd + (size_t)d1 * xds + f0);
    f32x2 wv = *(const f32x2*)(ew + f0);
    f32x2 bv = *(const f32x2*)(eb + f0);
    float c = tptr[0] * 1.44269504088896f;
    const f32x2 zz = {0.f, 0.f};
    int s0a = RFL(off[d0]), s1a = RFL(off[d0 + 1]);
    int s0b = RFL(off[d1]), s1b = RFL(off[d1 + 1]);
    f32x2 dena = {0.f, 0.f}, numa = {0.f, 0.f};
    f32x2 denb = {0.f, 0.f}, numb = {0.f, 0.f};

#define EDGE2(u, av, den, num)                                      \
    {                                                               \
        f32x2 xv = {bf2f_lo(u), bf2f_hi(u)};                        \
        f32x2 m = __builtin_elementwise_max(xv + bv + (av)*wv, zz); \
        f32x2 e;                                                    \
        e.x = __builtin_amdgcn_exp2f(m.x * c);                      \
        e.y = __builtin_amdgcn_exp2f(m.y * c);                      \
        den += e;                                                   \
        num += m * e;                                               \
    }
#define EDGE2M(u, av, mk, den, num)                                 \
    {                                                               \
        f32x2 xv = {bf2f_lo(u), bf2f_hi(u)};                        \
        f32x2 m = __builtin_elementwise_max(xv + bv + (av)*wv, zz); \
        f32x2 e;                                                    \
        e.x = __builtin_amdgcn_exp2f(m.x * c) * (mk);               \
        e.y = __builtin_amdgcn_exp2f(m.y * c) * (mk);               \
        den += e;                                                   \
        num += m * e;                                               \
    }
#define LOADMETA(jv, ii, aa)                                   \
    {                                                          \
        int4 q0 = *(const int4*)(sedge + (jv));                \
        int4 q1 = *(const int4*)(sedge + (jv) + 2);            \
        int4 q2 = *(const int4*)(sedge + (jv) + 4);            \
        int4 q3 = *(const int4*)(sedge + (jv) + 6);            \
        ii[0] = RFL(q0.x); aa[0] = __int_as_float(RFL(q0.y));  \
        ii[1] = RFL(q0.z); aa[1] = __int_as_float(RFL(q0.w));  \
        ii[2] = RFL(q1.x); aa[2] = __int_as_float(RFL(q1.y));  \
        ii[3] = RFL(q1.z); aa[3] = __int_as_float(RFL(q1.w));  \
        ii[4] = RFL(q2.x); aa[4] = __int_as_float(RFL(q2.y));  \
        ii[5] = RFL(q2.z); aa[5] = __int_as_float(RFL(q2.w));  \
        ii[6] = RFL(q3.x); aa[6] = __int_as_float(RFL(q3.y));  \
        ii[7] = RFL(q3.z); aa[7] = __int_as_float(RFL(q3.w));  \
    }
#define GATHER8(ii, uu)                                                          \
    _Pragma("unroll") for (int k = 0; k < 8; k++) uu[k] =                        \
        *(const unsigned int*)(xs + (size_t)ii[k] * XSS + f0);

    int ja = s0a, jb = s0b;
    // joint full batches: 2 independent chains in flight
    while (ja + 8 <= s1a && jb + 8 <= s1b) {
        int ia[8], ib[8];
        float aa[8], ab[8];
        LOADMETA(ja, ia, aa)
        LOADMETA(jb, ib, ab)
        unsigned int ua[8], ub[8];
        GATHER8(ia, ua)
        GATHER8(ib, ub)
#pragma unroll
        for (int k = 0; k < 8; k++) EDGE2(ua[k], aa[k], dena, numa)
#pragma unroll
        for (int k = 0; k < 8; k++) EDGE2(ub[k], ab[k], denb, numb)
        ja += 8;
        jb += 8;
    }
    // drain whichever node still has full batches (at most one loop runs)
    while (ja + 8 <= s1a) {
        int ia[8];
        float aa[8];
        LOADMETA(ja, ia, aa)
        unsigned int ua[8];
        GATHER8(ia, ua)
#pragma unroll
        for (int k = 0; k < 8; k++) EDGE2(ua[k], aa[k], dena, numa)
        ja += 8;
    }
    while (jb + 8 <= s1b) {
        int ib[8];
        float ab[8];
        LOADMETA(jb, ib, ab)
        unsigned int ub[8];
        GATHER8(ib, ub)
#pragma unroll
        for (int k = 0; k < 8; k++) EDGE2(ub[k], ab[k], denb, numb)
        jb += 8;
    }
    // joint masked tails (index clamped to last valid edge; zero-degree -> row 0, mask 0)
    if (ja < s1a || jb < s1b) {
        int lasta = (s1a > s0a) ? s1a - 1 : 0;
        int lastb = (s1b > s0b) ? s1b - 1 : 0;
        int ia[8], ib[8];
        float aa[8], ab[8], ma[8], mb[8];
#pragma unroll
        for (int k = 0; k < 8; k++) {
            int jj = ja + k;
            int cl = (jj < s1a) ? jj : lasta;
            int2 p = sedge[cl];
            ia[k] = RFL(p.x);
            aa[k] = __int_as_float(RFL(p.y));
            ma[k] = (jj < s1a) ? 1.f : 0.f;
            jj = jb + k;
            cl = (jj < s1b) ? jj : lastb;
            int2 q = sedge[cl];
            ib[k] = RFL(q.x);
            ab[k] = __int_as_float(RFL(q.y));
            mb[k] = (jj < s1b) ? 1.f : 0.f;
        }
        unsigned int ua[8], ub[8];
        GATHER8(ia, ua)
        GATHER8(ib, ub)
#pragma unroll
        for (int k = 0; k < 8; k++) EDGE2M(ua[k], aa[k], ma[k], dena, numa)
#pragma unroll
        for (int k = 0; k < 8; k++) EDGE2M(ub[k], ab[k], mb[k], denb, numb)
    }
#undef EDGE2
#undef EDGE2M
#undef LOADMETA
#undef GATHER8
    float a0 = (s1a > s0a) ? (numa.x / dena.x + 1e-7f) : 0.f;
    float a1 = (s1a > s0a) ? (numa.y / dena.y + 1e-7f) : 0.f;
    float b0 = (s1b > s0b) ? (numb.x / denb.x + 1e-7f) : 0.f;
    float b1 = (s1b > s0b) ? (numb.y / denb.y + 1e-7f) : 0.f;
    unsigned int lo = f2bf(a0 + bf2f_lo(uda));
    unsigned int hi = f2bf(a1 + bf2f_hi(uda));
    *(unsigned int*)(outb + (size_t)d0 * Hh + f0) = lo | (hi << 16);
    lo = f2bf(b0 + bf2f_lo(udb));
    hi = f2bf(b1 + bf2f_hi(udb));
    *(unsigned int*)(outb + (size_t)d1 * Hh + f0) = lo | (hi << 16);
}

// ---------------- final norm + hierarchical mean-pool ----------------

#define PCHUNK 100

__global__ __launch_bounds__(128) void pool_kernel(
    const float* __restrict__ h, const int* __restrict__ batch,
    const float* __restrict__ g, const float* __restrict__ b,
    const float* __restrict__ m, const float* __restrict__ v,
    float* __restrict__ pooled, float* __restrict__ cnt) {
    int hh = threadIdx.x;
    int i0 = blockIdx.x * PCHUNK;
    int i1 = min(i0 + PCHUNK, Nn);
    if (i0 >= Nn) return;
    float gg = g[hh], bb = b[hh], mm = m[hh], inv = rsqrtf(v[hh] + 1e-5f);
    int cur = batch[i0];
    float sum = 0.f, c = 0.f;
    for (int i = i0; i < i1; i++) {
        int gid = batch[i];
        float val = fmaxf(gg * (h[(size_t)i * Hh + hh] - mm) * inv + bb, 0.f);
        if (gid != cur) {
            atomicAdd(&pooled[(size_t)cur * Hh + hh], sum);
            if (hh == 0) atomicAdd(&cnt[cur], c);
            cur = gid;
            sum = 0.f;
            c = 0.f;
        }
        sum += val;
        c += 1.f;
    }
    atomicAdd(&pooled[(size_t)cur * Hh + hh], sum);
    if (hh == 0) atomicAdd(&cnt[cur], c);
}

// ---------------- classifier ----------------

__global__ __launch_bounds__(128) void cls_kernel(const float* __restrict__ pooled,
                                                  const float* __restrict__ cnt,
                                                  const float* __restrict__ clinical,
                                                  const float* __restrict__ w,
                                                  const float* __restrict__ bias,
                                                  float* __restrict__ out) {
    int t = threadIdx.x;
    int g = t >> 1, c = t & 1;
    float inv = 1.f / fmaxf(cnt[g], 1.f);
    float s = bias[c];
    for (int j = 0; j < Hh; j++) s += pooled[g * Hh + j] * inv * w[j * NCc + c];
    for (int k = 0; k < Kk; k++) s += clinical[g * Kk + k] * w[(Hh + k) * NCc + c];
    out[g * NCc + c] = s;
}

// ---------------- launch ----------------

extern "C" void kernel_launch(void* const* d_in, const int* in_sizes, int n_in,
                              void* d_out, int out_size, void* d_ws, size_t ws_size,
                              hipStream_t stream) {
    const float* x = (const float*)d_in[0];
    const int* eidx = (const int*)d_in[1];
    const float* eattr = (const float*)d_in[2];
    const int* batch = (const int*)d_in[3];
    const float* clinical = (const float*)d_in[4];
    const float* lin_src_w = (const float*)d_in[5];
    const float* lin_src_b = (const float*)d_in[6];
    const float* lin_dst_w = (const float*)d_in[7];
    const float* lin_dst_b = (const float*)d_in[8];
    const float* edge_w = (const float*)d_in[9];
    const float* edge_b = (const float*)d_in[10];
    const float* tt = (const float*)d_in[11];
    const float* mlp_w1 = (const float*)d_in[12];
    const float* mlp_b1 = (const float*)d_in[13];
    const float* bn_g = (const float*)d_in[14];
    const float* bn_b = (const float*)d_in[15];
    const float* bn_m = (const float*)d_in[16];
    const float* bn_v = (const float*)d_in[17];
    const float* mlp_w2 = (const float*)d_in[18];
    const float* mlp_b2 = (const float*)d_in[19];
    const float* norm_g = (const float*)d_in[20];
    const float* norm_b = (const float*)d_in[21];
    const float* norm_m = (const float*)d_in[22];
    const float* norm_v = (const float*)d_in[23];
    const float* cls_w = (const float*)d_in[24];
    const float* cls_b = (const float*)d_in[25];
    float* out = (float*)d_out;

    const int* src = eidx;
    const int* dst = eidx + Ee;

    char* ws = (char*)d_ws;
    size_t off_b = 0;
    auto alloc = [&](size_t bytes) -> void* {
        void* p = ws + off_b;
        off_b += (bytes + 255) & ~(size_t)255;
        return p;
    };
    // All GEMM-touched buffers padded to MPAD rows (garbage pad rows never read).
    unsigned short* xsd = (unsigned short*)alloc((size_t)MPAD * 256 * 2);   // proj out
    unsigned short* rbuf = (unsigned short*)alloc((size_t)MPAD * Hh * 2);   // prenorm out
    unsigned short* aggout = (unsigned short*)alloc((size_t)MPAD * Hh * 2);
    unsigned short* xbf = (unsigned short*)alloc((size_t)MPAD * 256 * 2);
    float* hbuf = (float*)alloc((size_t)MPAD * Hh * 4);
    int* deg = (int*)alloc((Nn + 1) * 4);
    int* offp = (int*)alloc((Nn + 1) * 4);
    int* pos = (int*)alloc((size_t)Nn * 4);
    int* bsum = (int*)alloc(NB * 4);
    int* boff = (int*)alloc(NB * 4);
    int2* sedge = (int2*)alloc((size_t)Ee * 8);
    float* pooled = (float*)alloc((size_t)Gg * Hh * 4);
    float* cntb = (float*)alloc(Gg * 4);
    unsigned short* wt = (unsigned short*)alloc((size_t)327680 * 2);

    hipMemsetAsync(deg, 0, (Nn + 1) * 4, stream);
    hipMemsetAsync(pooled, 0, (size_t)Gg * Hh * 4, stream);
    hipMemsetAsync(cntb, 0, Gg * 4, stream);

    hist_kernel<<<(Ee + 255) / 256, 256, 0, stream>>>(dst, deg);
    bsum_kernel<<<NB, 256, 0, stream>>>(deg, bsum);
    bscan_kernel<<<1, 256, 0, stream>>>(bsum, boff, offp);
    offsets_kernel<<<NB, 256, 0, stream>>>(deg, boff, offp, pos);
    scatter_kernel<<<(Ee + 255) / 256, 256, 0, stream>>>(src, dst, eattr, pos, sedge);
    wconv_kernel<<<1280, 256, 0, stream>>>(lin_src_w, lin_dst_w, mlp_w1, mlp_w2, wt);
    xconv_kernel<<<(Nn * Cc / 8 + 255) / 256, 256, 0, stream>>>(x, xbf);

    const unsigned short* wt_proj = wt;
    const unsigned short* wt_w1 = wt + 65536;
    const unsigned short* wt_w2 = wt + 196608;

    // Fused projection: xsd[:, :128] = x@Wsrc+b, xsd[:, 128:] = x@Wdst+b
    dim3 gproj(2, MPAD / 128);
    proj_kernel<<<gproj, 256, 0, stream>>>(xbf, wt_proj, lin_src_b, lin_dst_b, xsd);

    for (int l = 0; l < Ll; l++) {
        if (l == 0) {
            agg_kernel<256><<<Nn / 8, 256, 0, stream>>>(xsd, xsd + 128, 256, sedge, offp,
                                                        edge_w + l * Hh, edge_b + l * Hh,
                                                        tt + l, aggout);
        } else {
            agg_kernel<128><<<Nn / 8, 256, 0, stream>>>(rbuf, rbuf, Hh, sedge, offp,
                                                        edge_w + l * Hh, edge_b + l * Hh,
                                                        tt + l, aggout);
        }
        const float* png = (l < Ll - 1) ? (norm_g + (l + 1) * Hh) : nullptr;
        const float* pnb = (l < Ll - 1) ? (norm_b + (l + 1) * Hh) : nullptr;
        const float* pnm = (l < Ll - 1) ? (norm_m + (l + 1) * Hh) : nullptr;
        const float* pnv = (l < Ll - 1) ? (norm_v + (l + 1) * Hh) : nullptr;
        mlp_kernel<<<MPAD / 64, 256, 0, stream>>>(
            aggout, wt_w1 + (size_t)l * 32768, wt_w2 + (size_t)l * 32768,
            mlp_b1 + l * 2 * Hh, bn_g + l * 2 * Hh, bn_b + l * 2 * Hh,
            bn_m + l * 2 * Hh, bn_v + l * 2 * Hh, mlp_b2 + l * Hh,
            png, pnb, pnm, pnv, hbuf, rbuf, (l == 0) ? 0 : 1);
    }

    pool_kernel<<<(Nn + PCHUNK - 1) / PCHUNK, 128, 0, stream>>>(hbuf, batch, norm_g, norm_b,
                                                                norm_m, norm_v, pooled, cntb);
    cls_kernel<<<1, 128, 0, stream>>>(pooled, cntb, clinical, cls_w, cls_b, out);
}

// Round 15
// 490.344 us; speedup vs baseline: 1.0770x; 1.0004x over previous
//
#include <hip/hip_runtime.h>
#include <math.h>

// Problem constants (from reference)
#define Nn 50000
#define MPAD 50048  // Nn padded to multiple of 128 (GEMM row tiles, no guards)
#define Ee 500000
#define Cc 256
#define Hh 128
#define Ll 4
#define Gg 64
#define Kk 8
#define NCc 2

#define NB 196  // ceil(Nn/256)

typedef __attribute__((ext_vector_type(8))) short short8;
typedef __attribute__((ext_vector_type(4))) float f32x4;
typedef __attribute__((ext_vector_type(2))) float f32x2;

#define RFL __builtin_amdgcn_readfirstlane

__device__ __forceinline__ unsigned short f2bf(float f) {
    union { float f; unsigned int u; } v;
    v.f = f;
    unsigned int u = v.u;
    return (unsigned short)((u + 0x7FFFu + ((u >> 16) & 1u)) >> 16);
}
__device__ __forceinline__ float bf2f(unsigned short s) {
    union { float f; unsigned int u; } v;
    v.u = ((unsigned int)s) << 16;
    return v.f;
}
__device__ __forceinline__ float bf2f_lo(unsigned int u) {
    union { float f; unsigned int u; } v;
    v.u = u << 16;
    return v.f;
}
__device__ __forceinline__ float bf2f_hi(unsigned int u) {
    union { float f; unsigned int u; } v;
    v.u = u & 0xffff0000u;
    return v.f;
}

// ---------------- CSR build ----------------

__global__ void hist_kernel(const int* __restrict__ dst, int* __restrict__ deg) {
    int e = blockIdx.x * 256 + threadIdx.x;
    if (e < Ee) atomicAdd(&deg[dst[e]], 1);
}

__global__ __launch_bounds__(256) void bsum_kernel(const int* __restrict__ deg,
                                                   int* __restrict__ bsum) {
    __shared__ int ws[4];
    int t = threadIdx.x;
    int i = blockIdx.x * 256 + t;
    int v = (i < Nn) ? deg[i] : 0;
#pragma unroll
    for (int o = 32; o; o >>= 1) v += __shfl_down(v, o, 64);
    if ((t & 63) == 0) ws[t >> 6] = v;
    __syncthreads();
    if (t == 0) bsum[blockIdx.x] = ws[0] + ws[1] + ws[2] + ws[3];
}

__global__ __launch_bounds__(256) void bscan_kernel(const int* __restrict__ bsum,
                                                    int* __restrict__ boff,
                                                    int* __restrict__ off) {
    __shared__ int sc[256];
    int t = threadIdx.x;
    int v = (t < NB) ? bsum[t] : 0;
    sc[t] = v;
    __syncthreads();
    for (int o = 1; o < 256; o <<= 1) {
        int u = (t >= o) ? sc[t - o] : 0;
        __syncthreads();
        sc[t] += u;
        __syncthreads();
    }
    if (t < NB) boff[t] = sc[t] - v;  // exclusive
    if (t == NB - 1) off[Nn] = sc[t];
}

__global__ __launch_bounds__(256) void offsets_kernel(const int* __restrict__ deg,
                                                      const int* __restrict__ boff,
                                                      int* __restrict__ off,
                                                      int* __restrict__ pos) {
    __shared__ int sc[256];
    int t = threadIdx.x;
    int i = blockIdx.x * 256 + t;
    int v = (i < Nn) ? deg[i] : 0;
    sc[t] = v;
    __syncthreads();
    for (int o = 1; o < 256; o <<= 1) {
        int u = (t >= o) ? sc[t - o] : 0;
        __syncthreads();
        sc[t] += u;
        __syncthreads();
    }
    int excl = sc[t] - v + boff[blockIdx.x];
    if (i < Nn) {
        off[i] = excl;
        pos[i] = excl;
    }
}

__global__ void scatter_kernel(const int* __restrict__ src, const int* __restrict__ dst,
                               const float* __restrict__ attr, int* __restrict__ pos,
                               int2* __restrict__ sedge) {
    int e = blockIdx.x * 256 + threadIdx.x;
    if (e < Ee) {
        int d = dst[e];
        int p = atomicAdd(&pos[d], 1);
        sedge[p] = make_int2(src[e], __float_as_int(attr[e]));
    }
}

// ---------------- weight convert + transpose to bf16 [N][K] ----------------
// wt layout: [0, 65536)            proj  [256 n][256 k]  (n<128: lin_src col, else lin_dst)
//            [65536, 196608)       w1[l] [256 n][128 k]
//            [196608, 327680)      w2[l] [128 n][256 k]

__global__ void wconv_kernel(const float* __restrict__ lin_src_w,
                             const float* __restrict__ lin_dst_w,
                             const float* __restrict__ mlp_w1,
                             const float* __restrict__ mlp_w2,
                             unsigned short* __restrict__ wt) {
    int idx = blockIdx.x * 256 + threadIdx.x;
    if (idx >= 327680) return;
    float val;
    if (idx < 65536) {
        int n = idx >> 8, k = idx & 255;
        val = (n < 128) ? lin_src_w[k * 128 + n] : lin_dst_w[k * 128 + (n - 128)];
    } else if (idx < 196608) {
        int r = idx - 65536;
        int l = r >> 15, e = r & 32767;
        int n = e >> 7, k = e & 127;
        val = mlp_w1[(size_t)l * 32768 + k * 256 + n];
    } else {
        int r = idx - 196608;
        int l = r >> 15, e = r & 32767;
        int n = e >> 8, k = e & 255;
        val = mlp_w2[(size_t)l * 32768 + k * 128 + n];
    }
    wt[idx] = f2bf(val);
}

// ---------------- x fp32 -> bf16 (one-time, vectorized) ----------------

__global__ __launch_bounds__(256) void xconv_kernel(const float* __restrict__ x,
                                                    unsigned short* __restrict__ xbf) {
    int idx = blockIdx.x * 256 + threadIdx.x;  // 8 elems per thread
    if (idx >= (Nn * Cc) / 8) return;
    const float4* p = (const float4*)(x) + (size_t)idx * 2;
    float4 v0 = p[0], v1 = p[1];
    unsigned short t[8];
    t[0] = f2bf(v0.x); t[1] = f2bf(v0.y); t[2] = f2bf(v0.z); t[3] = f2bf(v0.w);
    t[4] = f2bf(v1.x); t[5] = f2bf(v1.y); t[6] = f2bf(v1.z); t[7] = f2bf(v1.w);
    *(short8*)(xbf + (size_t)idx * 8) = *(short8*)t;
}

#define GLOAD16(gp, lp)                                                                       \
    __builtin_amdgcn_global_load_lds(                                                         \
        (const __attribute__((address_space(1))) unsigned int*)(gp),                          \
        (__attribute__((address_space(3))) unsigned int*)(lp), 16, 0, 0)

// ---------------- projection GEMM: xsd = x @ [Wsrc|Wdst] + [bsrc|bdst] ----------------
// 128x128 tile, BK=32, 4 waves, depth-2 prefetch (3 LDS buffers, counted vmcnt).
// Epilogue staged through LDS -> coalesced short8 stores.

__global__ __launch_bounds__(256) void proj_kernel(
    const unsigned short* __restrict__ A, const unsigned short* __restrict__ Bt,
    const float* __restrict__ bias, const float* __restrict__ bias2,
    unsigned short* __restrict__ Cout) {
    __shared__ __align__(16) unsigned short SH[24576];  // 48KB: 3xA(8KB) + 3xB(8KB); C reuse
    int tid = threadIdx.x;
    int wave = tid >> 6, lane = tid & 63;
    int wr = wave >> 1, wc = wave & 1;
    int lrow = lane & 15, quad = lane >> 4;
    int m0 = blockIdx.y * 128, n0 = blockIdx.x * 128;
    const int K = 256;

    const unsigned short* ag0 = A + (size_t)(m0 + (tid >> 2)) * K + (tid & 3) * 8;
    const unsigned short* ag1 = A + (size_t)(m0 + 64 + (tid >> 2)) * K + (tid & 3) * 8;
    const unsigned short* bg0 = Bt + (size_t)(n0 + (tid >> 2)) * K + (tid & 3) * 8;
    const unsigned short* bg1 = Bt + (size_t)(n0 + 64 + (tid >> 2)) * K + (tid & 3) * 8;

    f32x4 acc[4][4];
#pragma unroll
    for (int i = 0; i < 4; i++)
#pragma unroll
        for (int j = 0; j < 4; j++) acc[i][j] = (f32x4){0.f, 0.f, 0.f, 0.f};

    auto stage = [&](int buf, int koff) {
        GLOAD16(ag0 + koff, SH + buf * 4096 + wave * 512);
        GLOAD16(ag1 + koff, SH + buf * 4096 + 2048 + wave * 512);
        GLOAD16(bg0 + koff, SH + 12288 + buf * 4096 + wave * 512);
        GLOAD16(bg1 + koff, SH + 12288 + buf * 4096 + 2048 + wave * 512);
    };

    const int ntiles = 8;
    stage(0, 0);
    stage(1, 32);
    for (int t = 0; t < ntiles; ++t) {
        if (t + 1 < ntiles) {
            asm volatile("s_waitcnt vmcnt(4)\n\ts_barrier" ::: "memory");
        } else {
            asm volatile("s_waitcnt vmcnt(0)\n\ts_barrier" ::: "memory");
        }
        if (t + 2 < ntiles) stage((t + 2) % 3, (t + 2) * 32);
        int cur = t % 3;
        const unsigned short* As = SH + cur * 4096;
        const unsigned short* Bs = SH + 12288 + cur * 4096;
        short8 af[4], bfr[4];
#pragma unroll
        for (int mt = 0; mt < 4; mt++)
            af[mt] = *(const short8*)&As[(wr * 64 + mt * 16 + lrow) * 32 + quad * 8];
#pragma unroll
        for (int nf = 0; nf < 4; nf++)
            bfr[nf] = *(const short8*)&Bs[(wc * 64 + nf * 16 + lrow) * 32 + quad * 8];
#pragma unroll
        for (int mt = 0; mt < 4; mt++)
#pragma unroll
            for (int nf = 0; nf < 4; nf++)
                acc[mt][nf] = __builtin_amdgcn_mfma_f32_16x16x32_bf16(af[mt], bfr[nf],
                                                                     acc[mt][nf], 0, 0, 0);
    }

    __syncthreads();  // all frag reads done; reuse SH for C tile
    unsigned short* Cl = SH;  // [128][128] bf16 = 32KB
#pragma unroll
    for (int nf = 0; nf < 4; nf++) {
        int gc = n0 + wc * 64 + nf * 16 + lrow;
        float bs = (gc >= 128) ? bias2[gc - 128] : bias[gc];
        int col = wc * 64 + nf * 16 + lrow;
#pragma unroll
        for (int mt = 0; mt < 4; mt++)
#pragma unroll
            for (int r = 0; r < 4; r++)
                Cl[(wr * 64 + mt * 16 + quad * 4 + r) * 128 + col] = f2bf(acc[mt][nf][r] + bs);
    }
    __syncthreads();
#pragma unroll
    for (int p = 0; p < 8; p++) {
        int vid = p * 256 + tid;
        int row = vid >> 4, cg = (vid & 15) * 8;
        short8 v = *(const short8*)&Cl[row * 128 + cg];
        *(short8*)(Cout + (size_t)(m0 + row) * 256 + n0 + cg) = v;
    }
}

// ---------------- fused per-layer MLP (counted-vmcnt pipelines, round-14 fix) --------
// hbuf (+)= agg @ W1 -> BN -> ReLU -> @ W2 + b2; next-layer prenorm rbuf fused.
// Round-4/5 lesson finally applied here: per-tile __syncthreads drains vmcnt(0)
// including the just-issued prefetch, so mlp's "dbuf" was inert.  Now: proj-style
// 3-buffer depth-2 pipelines with fused {s_waitcnt vmcnt(N); s_barrier} per tile.
// A (16KB) staged ONCE as 4 resident K-panels (reused by both N-halves); phase 1
// runs N=256 in 2 halves (B1 tiles 8KB, LPT=2, 8 stages); phase 2 runs N=128 in
// 2 halves (B2 tiles 4KB, LPT=1, 16 stages).  WAR safety: stage s reuses buf s%3
// whose reader (s-3) completed before the barrier at iter s-2 where s is issued.
// LDS arena 46,080B (A+B1 40KB | Hm 33.8KB + B2 12KB | C2 33.8KB) -> 3 blocks/CU.

__global__ __launch_bounds__(256) void mlp_kernel(
    const unsigned short* __restrict__ A,    // aggout [MPAD][128] bf16
    const unsigned short* __restrict__ W1,   // [256 n][128 k] bf16
    const unsigned short* __restrict__ W2,   // [128 n][256 k] bf16
    const float* __restrict__ b1, const float* __restrict__ bn_g,
    const float* __restrict__ bn_b, const float* __restrict__ bn_m,
    const float* __restrict__ bn_v, const float* __restrict__ b2,
    const float* __restrict__ pn_g, const float* __restrict__ pn_b,
    const float* __restrict__ pn_m, const float* __restrict__ pn_v,
    float* __restrict__ hbuf, unsigned short* __restrict__ rbuf, int rmw) {
    __shared__ __align__(16) unsigned short LDS_[23040];  // 46,080 B arena
    unsigned short* Ap = LDS_;             // A panels: 4 x [64][32] @ [0,8192) shorts
    unsigned short* B1 = LDS_ + 8192;      // 3 bufs x [128][32]    @ [8192,20480)
    unsigned short* Hm = LDS_;             // [64][264]             @ [0,16896)
    unsigned short* B2 = LDS_ + 16896;     // 3 bufs x [64][32]     @ [16896,23040)

    int tid = threadIdx.x;
    int wave = tid >> 6, lane = tid & 63;
    int lrow = lane & 15, quad = lane >> 4;
    int m0 = blockIdx.x * 64;

    // resident A: 4 K-panels staged once (4 gload16/thread)
    {
        const unsigned short* as = A + (size_t)(m0 + (tid >> 2)) * 128 + (tid & 3) * 8;
#pragma unroll
        for (int t = 0; t < 4; t++) GLOAD16(as + t * 32, Ap + t * 2048 + wave * 512);
    }
    const unsigned short* w1base = W1 + (size_t)(tid >> 2) * 128 + (tid & 3) * 8;
    auto stageB1 = [&](int s, int b) {  // s = h*4 + t
        int h = s >> 2, t = s & 3;
        const unsigned short* p = w1base + (size_t)h * 128 * 128 + t * 32;
        GLOAD16(p, B1 + b * 4096 + wave * 512);
        GLOAD16(p + (size_t)64 * 128, B1 + b * 4096 + 2048 + wave * 512);
    };
    stageB1(0, 0);
    stageB1(1, 1);

    f32x4 acc1a[4][2], acc1b[4][2];
#pragma unroll
    for (int i = 0; i < 4; i++)
#pragma unroll
        for (int j = 0; j < 2; j++) {
            acc1a[i][j] = (f32x4){0.f, 0.f, 0.f, 0.f};
            acc1b[i][j] = (f32x4){0.f, 0.f, 0.f, 0.f};
        }

    // phase 1, N-half 0 (cols 0..127): s = t
#pragma unroll
    for (int t = 0; t < 4; t++) {
        asm volatile("s_waitcnt vmcnt(2)\n\ts_barrier" ::: "memory");
        stageB1(t + 2, (t + 2) % 3);
        const unsigned short* Apan = Ap + t * 2048;
        const unsigned short* Bs = B1 + (t % 3) * 4096;
        short8 af[4], bfr[2];
#pragma unroll
        for (int mt = 0; mt < 4; mt++)
            af[mt] = *(const short8*)&Apan[(mt * 16 + lrow) * 32 + quad * 8];
#pragma unroll
        for (int nf = 0; nf < 2; nf++)
            bfr[nf] = *(const short8*)&Bs[(wave * 32 + nf * 16 + lrow) * 32 + quad * 8];
#pragma unroll
        for (int mt = 0; mt < 4; mt++)
#pragma unroll
            for (int nf = 0; nf < 2; nf++)
                acc1a[mt][nf] = __builtin_amdgcn_mfma_f32_16x16x32_bf16(af[mt], bfr[nf],
                                                                       acc1a[mt][nf], 0, 0, 0);
    }
    // phase 1, N-half 1 (cols 128..255): s = 4 + t
#pragma unroll
    for (int t = 0; t < 4; t++) {
        if (t < 3) {
            asm volatile("s_waitcnt vmcnt(2)\n\ts_barrier" ::: "memory");
        } else {
            asm volatile("s_waitcnt vmcnt(0)\n\ts_barrier" ::: "memory");
        }
        if (t < 2) stageB1(6 + t, (6 + t) % 3);
        const unsigned short* Apan = Ap + t * 2048;
        const unsigned short* Bs = B1 + ((4 + t) % 3) * 4096;
        short8 af[4], bfr[2];
#pragma unroll
        for (int mt = 0; mt < 4; mt++)
            af[mt] = *(const short8*)&Apan[(mt * 16 + lrow) * 32 + quad * 8];
#pragma unroll
        for (int nf = 0; nf < 2; nf++)
            bfr[nf] = *(const short8*)&Bs[(wave * 32 + nf * 16 + lrow) * 32 + quad * 8];
#pragma unroll
        for (int mt = 0; mt < 4; mt++)
#pragma unroll
            for (int nf = 0; nf < 2; nf++)
                acc1b[mt][nf] = __builtin_amdgcn_mfma_f32_16x16x32_bf16(af[mt], bfr[nf],
                                                                       acc1b[mt][nf], 0, 0, 0);
    }
    __syncthreads();  // all phase-1 LDS reads done; arena reusable

    const unsigned short* w2base = W2 + (size_t)(tid >> 2) * 256 + (tid & 3) * 8;
    auto stageB2 = [&](int s, int b) {  // s = h*8 + t
        int h = s >> 3, t = s & 7;
        GLOAD16(w2base + (size_t)h * 64 * 256 + t * 32, B2 + b * 2048 + wave * 512);
    };
    stageB2(0, 0);  // issued early; drained by the __syncthreads below (still overlaps
    stageB2(1, 1);  // the epilogue-1 compute before it)

    // epilogue 1 -> Hm
#pragma unroll
    for (int nf = 0; nf < 2; nf++) {
        int gc = wave * 32 + nf * 16 + lrow;  // half 0
        float bs = b1[gc];
        float g = bn_g[gc], bb = bn_b[gc], mm = bn_m[gc];
        float inv = rsqrtf(bn_v[gc] + 1e-5f);
#pragma unroll
        for (int mt = 0; mt < 4; mt++)
#pragma unroll
            for (int r = 0; r < 4; r++) {
                float v = acc1a[mt][nf][r] + bs;
                v = fmaxf(g * (v - mm) * inv + bb, 0.f);
                Hm[(mt * 16 + quad * 4 + r) * 264 + gc] = f2bf(v);
            }
    }
#pragma unroll
    for (int nf = 0; nf < 2; nf++) {
        int gc = 128 + wave * 32 + nf * 16 + lrow;  // half 1
        float bs = b1[gc];
        float g = bn_g[gc], bb = bn_b[gc], mm = bn_m[gc];
        float inv = rsqrtf(bn_v[gc] + 1e-5f);
#pragma unroll
        for (int mt = 0; mt < 4; mt++)
#pragma unroll
            for (int r = 0; r < 4; r++) {
                float v = acc1b[mt][nf][r] + bs;
                v = fmaxf(g * (v - mm) * inv + bb, 0.f);
                Hm[(mt * 16 + quad * 4 + r) * 264 + gc] = f2bf(v);
            }
    }
    __syncthreads();  // Hm visible (and B2(0),B2(1) drained)

    // phase 2: C2 = Hm @ W2 + b2, N in 2 halves of 64 cols
    f32x4 acc2a[4], acc2b[4];
#pragma unroll
    for (int i = 0; i < 4; i++) {
        acc2a[i] = (f32x4){0.f, 0.f, 0.f, 0.f};
        acc2b[i] = (f32x4){0.f, 0.f, 0.f, 0.f};
    }
#pragma unroll
    for (int t = 0; t < 8; t++) {  // half 0: s = t
        asm volatile("s_waitcnt vmcnt(1)\n\ts_barrier" ::: "memory");
        stageB2(t + 2, (t + 2) % 3);
        const unsigned short* Bs = B2 + (t % 3) * 2048;
        short8 af[4];
#pragma unroll
        for (int mt = 0; mt < 4; mt++)
            af[mt] = *(const short8*)&Hm[(mt * 16 + lrow) * 264 + t * 32 + quad * 8];
        short8 bf = *(const short8*)&Bs[(wave * 16 + lrow) * 32 + quad * 8];
#pragma unroll
        for (int mt = 0; mt < 4; mt++)
            acc2a[mt] = __builtin_amdgcn_mfma_f32_16x16x32_bf16(af[mt], bf, acc2a[mt], 0, 0, 0);
    }
#pragma unroll
    for (int t = 0; t < 8; t++) {  // half 1: s = 8 + t
        if (t < 7) {
            asm volatile("s_waitcnt vmcnt(1)\n\ts_barrier" ::: "memory");
        } else {
            asm volatile("s_waitcnt vmcnt(0)\n\ts_barrier" ::: "memory");
        }
        if (t < 6) stageB2(10 + t, (10 + t) % 3);
        const unsigned short* Bs = B2 + ((8 + t) % 3) * 2048;
        short8 af[4];
#pragma unroll
        for (int mt = 0; mt < 4; mt++)
            af[mt] = *(const short8*)&Hm[(mt * 16 + lrow) * 264 + t * 32 + quad * 8];
        short8 bf = *(const short8*)&Bs[(wave * 16 + lrow) * 32 + quad * 8];
#pragma unroll
        for (int mt = 0; mt < 4; mt++)
            acc2b[mt] = __builtin_amdgcn_mfma_f32_16x16x32_bf16(af[mt], bf, acc2b[mt], 0, 0, 0);
    }
    __syncthreads();  // all Hm/B2 reads done; reuse arena as fp32 C2 [64][132]

    float* C2 = (float*)LDS_;
    {
        int gc0 = wave * 16 + lrow, gc1 = 64 + wave * 16 + lrow;
        float bs0 = b2[gc0], bs1 = b2[gc1];
#pragma unroll
        for (int mt = 0; mt < 4; mt++)
#pragma unroll
            for (int r = 0; r < 4; r++) {
                C2[(mt * 16 + quad * 4 + r) * 132 + gc0] = acc2a[mt][r] + bs0;
                C2[(mt * 16 + quad * 4 + r) * 132 + gc1] = acc2b[mt][r] + bs1;
            }
    }
    __syncthreads();
#pragma unroll
    for (int p = 0; p < 8; p++) {
        int vid = p * 256 + tid;
        int row = vid >> 5, c4 = (vid & 31) * 4;
        f32x4 v = *(const f32x4*)&C2[row * 132 + c4];
        float* hp = hbuf + (size_t)(m0 + row) * 128 + c4;
        if (rmw) v += *(const f32x4*)hp;
        *(f32x4*)hp = v;
        if (pn_g) {
            f32x4 pg = *(const f32x4*)&pn_g[c4];
            f32x4 pb = *(const f32x4*)&pn_b[c4];
            f32x4 pm = *(const f32x4*)&pn_m[c4];
            f32x4 pv = *(const f32x4*)&pn_v[c4];
            float r0 = fmaxf(pg[0] * (v[0] - pm[0]) * rsqrtf(pv[0] + 1e-5f) + pb[0], 0.f);
            float r1 = fmaxf(pg[1] * (v[1] - pm[1]) * rsqrtf(pv[1] + 1e-5f) + pb[1], 0.f);
            float r2 = fmaxf(pg[2] * (v[2] - pm[2]) * rsqrtf(pv[2] + 1e-5f) + pb[2], 0.f);
            float r3 = fmaxf(pg[3] * (v[3] - pm[3]) * rsqrtf(pv[3] + 1e-5f) + pb[3], 0.f);
            unsigned int w0 = (unsigned int)f2bf(r0) | ((unsigned int)f2bf(r1) << 16);
            unsigned int w1 = (unsigned int)f2bf(r2) | ((unsigned int)f2bf(r3) << 16);
            uint2 pk = make_uint2(w0, w1);
            *(uint2*)(rbuf + (size_t)(m0 + row) * 128 + c4) = pk;
        }
    }
}

// ---------------- Fused GENConv aggregation (2 nodes/wave, interleaved chains) --------
// Each wave owns nodes d0,d1; main loop keeps both nodes' gather chains in flight
// (round 11/12: -4us/dispatch vs 1 node/wave).  All wave-uniform control scalarized
// via readfirstlane (round-10 win).  Per-edge +1e-7 folded into the final quotient.

template <int XSS>
__global__ __launch_bounds__(256) void agg_kernel(
    const unsigned short* __restrict__ xs,
    const unsigned short* __restrict__ xd, int xds,
    const int2* __restrict__ sedge, const int* __restrict__ off,
    const float* __restrict__ ew, const float* __restrict__ eb,
    const float* __restrict__ tptr, unsigned short* __restrict__ outb) {
    int wave = threadIdx.x >> 6;
    int lane = threadIdx.x & 63;
    int d0 = blockIdx.x * 8 + wave * 2;  // Nn % 8 == 0, d0,d1 always < Nn
    int d1 = d0 + 1;
    int f0 = lane * 2;
    unsigned int uda = *(const unsigned int*)(xd + (size_t)d0 * xds + f0);
    unsigned int udb = *(const unsigned int*)(xd + (size_t)d1 * xds + f0);
    f32x2 wv = *(const f32x2*)(ew + f0);
    f32x2 bv = *(const f32x2*)(eb + f0);
    float c = tptr[0] * 1.44269504088896f;
    const f32x2 zz = {0.f, 0.f};
    int s0a = RFL(off[d0]), s1a = RFL(off[d0 + 1]);
    int s0b = RFL(off[d1]), s1b = RFL(off[d1 + 1]);
    f32x2 dena = {0.f, 0.f}, numa = {0.f, 0.f};
    f32x2 denb = {0.f, 0.f}, numb = {0.f, 0.f};

#define EDGE2(u, av, den, num)                                      \
    {                                                               \
        f32x2 xv = {bf2f_lo(u), bf2f_hi(u)};                        \
        f32x2 m = __builtin_elementwise_max(xv + bv + (av)*wv, zz); \
        f32x2 e;                                                    \
        e.x = __builtin_amdgcn_exp2f(m.x * c);                      \
        e.y = __builtin_amdgcn_exp2f(m.y * c);                      \
        den += e;                                                   \
        num += m * e;                                               \
    }
#define EDGE2M(u, av, mk, den, num)                                 \
    {                                                               \
        f32x2 xv = {bf2f_lo(u), bf2f_hi(u)};                        \
        f32x2 m = __builtin_elementwise_max(xv + bv + (av)*wv, zz); \
        f32x2 e;                                                    \
        e.x = __builtin_amdgcn_exp2f(m.x * c) * (mk);               \
        e.y = __builtin_amdgcn_exp2f(m.y * c) * (mk);               \
        den += e;                                                   \
        num += m * e;                                               \
    }
#define LOADMETA(jv, ii, aa)                                   \
    {                                                          \
        int4 q0 = *(const int4*)(sedge + (jv));                \
        int4 q1 = *(const int4*)(sedge + (jv) + 2);            \
        int4 q2 = *(const int4*)(sedge + (jv) + 4);            \
        int4 q3 = *(const int4*)(sedge + (jv) + 6);            \
        ii[0] = RFL(q0.x); aa[0] = __int_as_float(RFL(q0.y));  \
        ii[1] = RFL(q0.z); aa[1] = __int_as_float(RFL(q0.w));  \
        ii[2] = RFL(q1.x); aa[2] = __int_as_float(RFL(q1.y));  \
        ii[3] = RFL(q1.z); aa[3] = __int_as_float(RFL(q1.w));  \
        ii[4] = RFL(q2.x); aa[4] = __int_as_float(RFL(q2.y));  \
        ii[5] = RFL(q2.z); aa[5] = __int_as_float(RFL(q2.w));  \
        ii[6] = RFL(q3.x); aa[6] = __int_as_float(RFL(q3.y));  \
        ii[7] = RFL(q3.z); aa[7] = __int_as_float(RFL(q3.w));  \
    }
#define GATHER8(ii, uu)                                                          \
    _Pragma("unroll") for (int k = 0; k < 8; k++) uu[k] =                        \
        *(const unsigned int*)(xs + (size_t)ii[k] * XSS + f0);

    int ja = s0a, jb = s0b;
    // joint full batches: 2 independent chains in flight
    while (ja + 8 <= s1a && jb + 8 <= s1b) {
        int ia[8], ib[8];
        float aa[8], ab[8];
        LOADMETA(ja, ia, aa)
        LOADMETA(jb, ib, ab)
        unsigned int ua[8], ub[8];
        GATHER8(ia, ua)
        GATHER8(ib, ub)
#pragma unroll
        for (int k = 0; k < 8; k++) EDGE2(ua[k], aa[k], dena, numa)
#pragma unroll
        for (int k = 0; k < 8; k++) EDGE2(ub[k], ab[k], denb, numb)
        ja += 8;
        jb += 8;
    }
    // drain whichever node still has full batches (at most one loop runs)
    while (ja + 8 <= s1a) {
        int ia[8];
        float aa[8];
        LOADMETA(ja, ia, aa)
        unsigned int ua[8];
        GATHER8(ia, ua)
#pragma unroll
        for (int k = 0; k < 8; k++) EDGE2(ua[k], aa[k], dena, numa)
        ja += 8;
    }
    while (jb + 8 <= s1b) {
        int ib[8];
        float ab[8];
        LOADMETA(jb, ib, ab)
        unsigned int ub[8];
        GATHER8(ib, ub)
#pragma unroll
        for (int k = 0; k < 8; k++) EDGE2(ub[k], ab[k], denb, numb)
        jb += 8;
    }
    // joint masked tails (index clamped to last valid edge; zero-degree -> row 0, mask 0)
    if (ja < s1a || jb < s1b) {
        int lasta = (s1a > s0a) ? s1a - 1 : 0;
        int lastb = (s1b > s0b) ? s1b - 1 : 0;
        int ia[8], ib[8];
        float aa[8], ab[8], ma[8], mb[8];
#pragma unroll
        for (int k = 0; k < 8; k++) {
            int jj = ja + k;
            int cl = (jj < s1a) ? jj : lasta;
            int2 p = sedge[cl];
            ia[k] = RFL(p.x);
            aa[k] = __int_as_float(RFL(p.y));
            ma[k] = (jj < s1a) ? 1.f : 0.f;
            jj = jb + k;
            cl = (jj < s1b) ? jj : lastb;
            int2 q = sedge[cl];
            ib[k] = RFL(q.x);
            ab[k] = __int_as_float(RFL(q.y));
            mb[k] = (jj < s1b) ? 1.f : 0.f;
        }
        unsigned int ua[8], ub[8];
        GATHER8(ia, ua)
        GATHER8(ib, ub)
#pragma unroll
        for (int k = 0; k < 8; k++) EDGE2M(ua[k], aa[k], ma[k], dena, numa)
#pragma unroll
        for (int k = 0; k < 8; k++) EDGE2M(ub[k], ab[k], mb[k], denb, numb)
    }
#undef EDGE2
#undef EDGE2M
#undef LOADMETA
#undef GATHER8
    float a0 = (s1a > s0a) ? (numa.x / dena.x + 1e-7f) : 0.f;
    float a1 = (s1a > s0a) ? (numa.y / dena.y + 1e-7f) : 0.f;
    float b0 = (s1b > s0b) ? (numb.x / denb.x + 1e-7f) : 0.f;
    float b1 = (s1b > s0b) ? (numb.y / denb.y + 1e-7f) : 0.f;
    unsigned int lo = f2bf(a0 + bf2f_lo(uda));
    unsigned int hi = f2bf(a1 + bf2f_hi(uda));
    *(unsigned int*)(outb + (size_t)d0 * Hh + f0) = lo | (hi << 16);
    lo = f2bf(b0 + bf2f_lo(udb));
    hi = f2bf(b1 + bf2f_hi(udb));
    *(unsigned int*)(outb + (size_t)d1 * Hh + f0) = lo | (hi << 16);
}

// ---------------- final norm + hierarchical mean-pool ----------------

#define PCHUNK 100

__global__ __launch_bounds__(128) void pool_kernel(
    const float* __restrict__ h, const int* __restrict__ batch,
    const float* __restrict__ g, const float* __restrict__ b,
    const float* __restrict__ m, const float* __restrict__ v,
    float* __restrict__ pooled, float* __restrict__ cnt) {
    int hh = threadIdx.x;
    int i0 = blockIdx.x * PCHUNK;
    int i1 = min(i0 + PCHUNK, Nn);
    if (i0 >= Nn) return;
    float gg = g[hh], bb = b[hh], mm = m[hh], inv = rsqrtf(v[hh] + 1e-5f);
    int cur = batch[i0];
    float sum = 0.f, c = 0.f;
    for (int i = i0; i < i1; i++) {
        int gid = batch[i];
        float val = fmaxf(gg * (h[(size_t)i * Hh + hh] - mm) * inv + bb, 0.f);
        if (gid != cur) {
            atomicAdd(&pooled[(size_t)cur * Hh + hh], sum);
            if (hh == 0) atomicAdd(&cnt[cur], c);
            cur = gid;
            sum = 0.f;
            c = 0.f;
        }
        sum += val;
        c += 1.f;
    }
    atomicAdd(&pooled[(size_t)cur * Hh + hh], sum);
    if (hh == 0) atomicAdd(&cnt[cur], c);
}

// ---------------- classifier ----------------

__global__ __launch_bounds__(128) void cls_kernel(const float* __restrict__ pooled,
                                                  const float* __restrict__ cnt,
                                                  const float* __restrict__ clinical,
                                                  const float* __restrict__ w,
                                                  const float* __restrict__ bias,
                                                  float* __restrict__ out) {
    int t = threadIdx.x;
    int g = t >> 1, c = t & 1;
    float inv = 1.f / fmaxf(cnt[g], 1.f);
    float s = bias[c];
    for (int j = 0; j < Hh; j++) s += pooled[g * Hh + j] * inv * w[j * NCc + c];
    for (int k = 0; k < Kk; k++) s += clinical[g * Kk + k] * w[(Hh + k) * NCc + c];
    out[g * NCc + c] = s;
}

// ---------------- launch ----------------

extern "C" void kernel_launch(void* const* d_in, const int* in_sizes, int n_in,
                              void* d_out, int out_size, void* d_ws, size_t ws_size,
                              hipStream_t stream) {
    const float* x = (const float*)d_in[0];
    const int* eidx = (const int*)d_in[1];
    const float* eattr = (const float*)d_in[2];
    const int* batch = (const int*)d_in[3];
    const float* clinical = (const float*)d_in[4];
    const float* lin_src_w = (const float*)d_in[5];
    const float* lin_src_b = (const float*)d_in[6];
    const float* lin_dst_w = (const float*)d_in[7];
    const float* lin_dst_b = (const float*)d_in[8];
    const float* edge_w = (const float*)d_in[9];
    const float* edge_b = (const float*)d_in[10];
    const float* tt = (const float*)d_in[11];
    const float* mlp_w1 = (const float*)d_in[12];
    const float* mlp_b1 = (const float*)d_in[13];
    const float* bn_g = (const float*)d_in[14];
    const float* bn_b = (const float*)d_in[15];
    const float* bn_m = (const float*)d_in[16];
    const float* bn_v = (const float*)d_in[17];
    const float* mlp_w2 = (const float*)d_in[18];
    const float* mlp_b2 = (const float*)d_in[19];
    const float* norm_g = (const float*)d_in[20];
    const float* norm_b = (const float*)d_in[21];
    const float* norm_m = (const float*)d_in[22];
    const float* norm_v = (const float*)d_in[23];
    const float* cls_w = (const float*)d_in[24];
    const float* cls_b = (const float*)d_in[25];
    float* out = (float*)d_out;

    const int* src = eidx;
    const int* dst = eidx + Ee;

    char* ws = (char*)d_ws;
    size_t off_b = 0;
    auto alloc = [&](size_t bytes) -> void* {
        void* p = ws + off_b;
        off_b += (bytes + 255) & ~(size_t)255;
        return p;
    };
    // deg/pooled/cntb contiguous -> ONE memset covers all three (saves 2 dispatches)
    int* deg = (int*)alloc((Nn + 1) * 4);          // 200192 B padded
    float* pooled = (float*)alloc((size_t)Gg * Hh * 4);  // 32768 B
    float* cntb = (float*)alloc(Gg * 4);           // 256 B
    // All GEMM-touched buffers padded to MPAD rows (garbage pad rows never read).
    unsigned short* xsd = (unsigned short*)alloc((size_t)MPAD * 256 * 2);   // proj out
    unsigned short* rbuf = (unsigned short*)alloc((size_t)MPAD * Hh * 2);   // prenorm out
    unsigned short* aggout = (unsigned short*)alloc((size_t)MPAD * Hh * 2);
    unsigned short* xbf = (unsigned short*)alloc((size_t)MPAD * 256 * 2);
    float* hbuf = (float*)alloc((size_t)MPAD * Hh * 4);
    int* offp = (int*)alloc((Nn + 1) * 4);
    int* pos = (int*)alloc((size_t)Nn * 4);
    int* bsum = (int*)alloc(NB * 4);
    int* boff = (int*)alloc(NB * 4);
    int2* sedge = (int2*)alloc((size_t)Ee * 8);
    unsigned short* wt = (unsigned short*)alloc((size_t)327680 * 2);

    hipMemsetAsync(deg, 0, 200192 + 32768 + 256, stream);  // deg + pooled + cntb

    hist_kernel<<<(Ee + 255) / 256, 256, 0, stream>>>(dst, deg);
    bsum_kernel<<<NB, 256, 0, stream>>>(deg, bsum);
    bscan_kernel<<<1, 256, 0, stream>>>(bsum, boff, offp);
    offsets_kernel<<<NB, 256, 0, stream>>>(deg, boff, offp, pos);
    scatter_kernel<<<(Ee + 255) / 256, 256, 0, stream>>>(src, dst, eattr, pos, sedge);
    wconv_kernel<<<1280, 256, 0, stream>>>(lin_src_w, lin_dst_w, mlp_w1, mlp_w2, wt);
    xconv_kernel<<<(Nn * Cc / 8 + 255) / 256, 256, 0, stream>>>(x, xbf);

    const unsigned short* wt_proj = wt;
    const unsigned short* wt_w1 = wt + 65536;
    const unsigned short* wt_w2 = wt + 196608;

    // Fused projection: xsd[:, :128] = x@Wsrc+b, xsd[:, 128:] = x@Wdst+b
    dim3 gproj(2, MPAD / 128);
    proj_kernel<<<gproj, 256, 0, stream>>>(xbf, wt_proj, lin_src_b, lin_dst_b, xsd);

    for (int l = 0; l < Ll; l++) {
        if (l == 0) {
            agg_kernel<256><<<Nn / 8, 256, 0, stream>>>(xsd, xsd + 128, 256, sedge, offp,
                                                        edge_w + l * Hh, edge_b + l * Hh,
                                                        tt + l, aggout);
        } else {
            agg_kernel<128><<<Nn / 8, 256, 0, stream>>>(rbuf, rbuf, Hh, sedge, offp,
                                                        edge_w + l * Hh, edge_b + l * Hh,
                                                        tt + l, aggout);
        }
        const float* png = (l < Ll - 1) ? (norm_g + (l + 1) * Hh) : nullptr;
        const float* pnb = (l < Ll - 1) ? (norm_b + (l + 1) * Hh) : nullptr;
        const float* pnm = (l < Ll - 1) ? (norm_m + (l + 1) * Hh) : nullptr;
        const float* pnv = (l < Ll - 1) ? (norm_v + (l + 1) * Hh) : nullptr;
        mlp_kernel<<<MPAD / 64, 256, 0, stream>>>(
            aggout, wt_w1 + (size_t)l * 32768, wt_w2 + (size_t)l * 32768,
            mlp_b1 + l * 2 * Hh, bn_g + l * 2 * Hh, bn_b + l * 2 * Hh,
            bn_m + l * 2 * Hh, bn_v + l * 2 * Hh, mlp_b2 + l * Hh,
            png, pnb, pnm, pnv, hbuf, rbuf, (l == 0) ? 0 : 1);
    }

    pool_kernel<<<(Nn + PCHUNK - 1) / PCHUNK, 128, 0, stream>>>(hbuf, batch, norm_g, norm_b,
                                                                norm_m, norm_v, pooled, cntb);
    cls_kernel<<<1, 128, 0, stream>>>(pooled, cntb, clinical, cls_w, cls_b, out);
}